// Round 17
// baseline (749.461 us; speedup 1.0000x reference)
//
#include <hip/hip_runtime.h>
#define S_LEN 2048
#define HDIM 4096
#define NHEAD 32
#define QKD 192
#define RQ_ 1536
#define CKV_W 576
#define KVW 8192
#define QFW 6144
#define SC2F 0.1041216313667742f

typedef float f32x4 __attribute__((ext_vector_type(4)));
typedef __bf16 bf16x8 __attribute__((ext_vector_type(8)));

__device__ __forceinline__ unsigned short f2bf(float f) {
  unsigned int u = __float_as_uint(f);
  u += 0x7fffu + ((u >> 16) & 1u);
  return (unsigned short)(u >> 16);
}
__device__ __forceinline__ unsigned int pk2(float a, float b) {
  return (unsigned int)f2bf(a) | ((unsigned int)f2bf(b) << 16);
}
__device__ __forceinline__ float b2f(unsigned short u) {
  return __uint_as_float((unsigned int)u << 16);
}
__device__ __forceinline__ float ex2(float x) { return exp2f(x); }

__device__ __forceinline__ void stage16(const void* g, void* lds_base, int lane) {
  __builtin_amdgcn_global_load_lds(
      (const __attribute__((address_space(1))) unsigned int*)g,
      (__attribute__((address_space(3))) unsigned int*)lds_base, 16, 0, 0);
}

__global__ __launch_bounds__(256) void cvt_kernel(
    const float* __restrict__ in, unsigned short* __restrict__ out, int n8) {
  int i = blockIdx.x * 256 + threadIdx.x;
  if (i >= n8) return;
  const float4* p = reinterpret_cast<const float4*>(in) + (size_t)i * 2;
  float4 a = p[0], b = p[1];
  unsigned long long lo = (unsigned long long)pk2(a.x, a.y)
      | ((unsigned long long)pk2(a.z, a.w) << 32);
  unsigned long long hi = (unsigned long long)pk2(b.x, b.y)
      | ((unsigned long long)pk2(b.z, b.w) << 32);
  unsigned long long* q = reinterpret_cast<unsigned long long*>(out) + (size_t)i * 2;
  q[0] = lo; q[1] = hi;
}

// BK=32 2-phase dbuf 128x128 GEMM, M-fast XCD decode (B-panel L2-resident).
// A: bf16 via global_load_lds. B: f32 weights, converted in-register while
// staging (fuses the weight cvt pass into the GEMM's idle stall window).
template<bool BF16OUT, bool SPLITK>
__global__ __launch_bounds__(256) void gemm_bf(
    const unsigned short* __restrict__ A, int lda,
    const float* __restrict__ B, int ldb,
    void* __restrict__ Cv, int ldc, int N, int K) {
  __shared__ unsigned short As[2][4][128][8];
  __shared__ unsigned short Bs[2][4][128][8];
  const int tid = threadIdx.x, lane = tid & 63, w = tid >> 6;
  const int gx = (int)gridDim.x, gy = (int)gridDim.y;
  const int nwg = gx * gy;
  int lin = (int)blockIdx.y * gx + (int)blockIdx.x;
  if ((nwg & 7) == 0) lin = (lin & 7) * (nwg >> 3) + (lin >> 3);
  const int bm = (lin % gy) * 128, bn = (lin / gy) * 128;
  const int koff = SPLITK ? (int)blockIdx.z * K : 0;
  const int wr = (w >> 1) * 64, wc = (w & 1) * 64;
  const int lg = lane >> 4, lm = lane & 15;
  f32x4 acc[4][4] = {};
  const int arow = bm + lane;
  int brow = bn + lane; if (brow >= N) brow = N - 1;

  auto STAGE = [&](int buf, int k0) {
#pragma unroll
    for (int i = 0; i < 2; ++i) {
      stage16(A + (size_t)(arow + i * 64) * lda + koff + k0 + w * 8, &As[buf][w][i * 64][0], lane);
    }
    // B: load f32, convert, ds_write (per-lane row i*64+lane, k-group w)
#pragma unroll
    for (int i = 0; i < 2; ++i) {
      int br2 = brow + i * 64; if (br2 >= N) br2 = N - 1;
      const float4* src = reinterpret_cast<const float4*>(
          B + (size_t)br2 * ldb + koff + k0 + w * 8);
      float4 a = src[0], b = src[1];
      uint4 pkd = make_uint4(pk2(a.x, a.y), pk2(a.z, a.w), pk2(b.x, b.y), pk2(b.z, b.w));
      *reinterpret_cast<uint4*>(&Bs[buf][w][i * 64 + lane][0]) = pkd;
    }
  };
  STAGE(0, 0);
  __syncthreads();
  int cur = 0;
  for (int k0 = 0; k0 < K; k0 += 32) {
    if (k0 + 32 < K) STAGE(cur ^ 1, k0 + 32);
    bf16x8 af[4], bf[4];
#pragma unroll
    for (int i = 0; i < 4; ++i)
      af[i] = *reinterpret_cast<const bf16x8*>(&As[cur][lg][wr + i * 16 + lm][0]);
#pragma unroll
    for (int j = 0; j < 4; ++j)
      bf[j] = *reinterpret_cast<const bf16x8*>(&Bs[cur][lg][wc + j * 16 + lm][0]);
    __builtin_amdgcn_s_setprio(1);
#pragma unroll
    for (int i = 0; i < 4; ++i)
#pragma unroll
      for (int j = 0; j < 4; ++j)
        acc[i][j] = __builtin_amdgcn_mfma_f32_16x16x32_bf16(af[i], bf[j], acc[i][j], 0, 0, 0);
    __builtin_amdgcn_s_setprio(0);
    __syncthreads();
    cur ^= 1;
  }
  size_t zoff = SPLITK ? (size_t)blockIdx.z * S_LEN * N : 0;
#pragma unroll
  for (int i = 0; i < 4; ++i)
#pragma unroll
    for (int j = 0; j < 4; ++j)
#pragma unroll
      for (int r = 0; r < 4; ++r) {
        int row = bm + wr + i * 16 + lg * 4 + r;
        int col = bn + wc + j * 16 + lm;
        if (col < N) {
          if constexpr (BF16OUT)
            ((unsigned short*)Cv)[(size_t)row * ldc + col] = f2bf(acc[i][j][r]);
          else
            ((float*)Cv)[zoff + (size_t)row * ldc + col] = acc[i][j][r];
        }
      }
}

__global__ __launch_bounds__(256) void rms_sum_q(
    const float* __restrict__ P, const float* __restrict__ w,
    unsigned short* __restrict__ y) {
  __shared__ float red[4];
  const int row = blockIdx.x, tid = threadIdx.x;
  const float* base = P + (size_t)row * RQ_;
  float x[6]; float ss = 0.f;
#pragma unroll
  for (int ii = 0; ii < 6; ++ii) {
    int j = tid + ii * 256;
    float v = 0.f;
#pragma unroll
    for (int z = 0; z < 4; ++z) v += base[(size_t)z * S_LEN * RQ_ + j];
    x[ii] = v; ss += v * v;
  }
#pragma unroll
  for (int off = 1; off < 64; off <<= 1) ss += __shfl_xor(ss, off, 64);
  if ((tid & 63) == 0) red[tid >> 6] = ss;
  __syncthreads();
  float scale = rsqrtf((red[0] + red[1] + red[2] + red[3]) / (float)RQ_ + 1e-6f);
  unsigned short* q = y + (size_t)row * RQ_;
#pragma unroll
  for (int ii = 0; ii < 6; ++ii) {
    int j = tid + ii * 256;
    q[j] = f2bf(x[ii] * scale * w[j]);
  }
}

__global__ __launch_bounds__(256) void rms_sum_kv(
    const float* __restrict__ P, const float* __restrict__ w,
    unsigned short* __restrict__ y, float* __restrict__ rotf) {
  __shared__ float red[4];
  const int row = blockIdx.x, tid = threadIdx.x;
  const float* base = P + (size_t)row * CKV_W;
  float x0 = 0.f, x1 = 0.f, x2 = 0.f;
#pragma unroll
  for (int z = 0; z < 8; ++z) {
    const float* b = base + (size_t)z * S_LEN * CKV_W;
    x0 += b[tid]; x1 += b[tid + 256];
    if (tid < 64) x2 += b[tid + 512];
  }
  float ss = x0 * x0 + x1 * x1;
#pragma unroll
  for (int off = 1; off < 64; off <<= 1) ss += __shfl_xor(ss, off, 64);
  if ((tid & 63) == 0) red[tid >> 6] = ss;
  __syncthreads();
  float scale = rsqrtf((red[0] + red[1] + red[2] + red[3]) / 512.0f + 1e-6f);
  unsigned short* q = y + (size_t)row * 512;
  q[tid] = f2bf(x0 * scale * w[tid]);
  q[tid + 256] = f2bf(x1 * scale * w[tid + 256]);
  if (tid < 64) rotf[(size_t)row * 64 + tid] = x2;
}

__global__ __launch_bounds__(256) void build_q_kernel(
    const unsigned short* __restrict__ qf, const float* __restrict__ freqs,
    unsigned short* __restrict__ Q) {
  int idx = blockIdx.x * 256 + threadIdx.x;
  if (idx >= NHEAD * S_LEN * 96) return;
  int j = idx % 96, s = (idx / 96) % S_LEN, h = idx / (96 * S_LEN);
  const unsigned short* src = qf + (size_t)s * QFW + h * QKD;
  unsigned int pk;
  if (j < 64) {
    pk = *reinterpret_cast<const unsigned int*>(&src[2 * j]);
  } else {
    int r = j - 64;
    float xr = b2f(src[128 + 2 * r]), xi = b2f(src[128 + 2 * r + 1]);
    float f = freqs[(size_t)s * 32 + r];
    float c = cosf(f), sn = sinf(f);
    pk = pk2(xr * c - xi * sn, xr * sn + xi * c);
  }
  *reinterpret_cast<unsigned int*>(Q + ((size_t)(h * S_LEN + s) * QKD + 2 * j)) = pk;
}

__global__ __launch_bounds__(256) void build_k_kernel(
    const unsigned short* __restrict__ kv, const float* __restrict__ rotf,
    const float* __restrict__ freqs, unsigned short* __restrict__ K) {
  int idx = blockIdx.x * 256 + threadIdx.x;
  if (idx >= NHEAD * S_LEN * 96) return;
  int j = idx % 96, s = (idx / 96) % S_LEN, h = idx / (96 * S_LEN);
  unsigned int pk;
  if (j < 64) {
    pk = *reinterpret_cast<const unsigned int*>(&kv[(size_t)s * KVW + h * 256 + 2 * j]);
  } else {
    int r = j - 64;
    float xr = rotf[(size_t)s * 64 + 2 * r];
    float xi = rotf[(size_t)s * 64 + 2 * r + 1];
    float f = freqs[(size_t)s * 32 + r];
    float c = cosf(f), sn = sinf(f);
    pk = pk2(xr * c - xi * sn, xr * sn + xi * c);
  }
  *reinterpret_cast<unsigned int*>(K + ((size_t)(h * S_LEN + s) * QKD + 2 * j)) = pk;
}

__global__ __launch_bounds__(256) void build_vt_kernel(
    const unsigned short* __restrict__ kv, unsigned short* __restrict__ Vt) {
  __shared__ unsigned short T[128][33];
  const int tid = threadIdx.x;
  const int h = blockIdx.y, s0 = blockIdx.x * 32;
#pragma unroll
  for (int p = 0; p < 16; ++p) {
    int i = p * 256 + tid;
    int d = i & 127, sr = i >> 7;
    T[d][sr] = kv[(size_t)(s0 + sr) * KVW + h * 256 + 128 + d];
  }
  __syncthreads();
#pragma unroll
  for (int p = 0; p < 8; ++p) {
    int i = p * 256 + tid;
    int d = i >> 4, sp = (i & 15) * 2;
    unsigned int pk = (unsigned int)T[d][sp] | ((unsigned int)T[d][sp + 1] << 16);
    *reinterpret_cast<unsigned int*>(Vt + (size_t)(h * 128 + d) * S_LEN + s0 + sp) = pk;
  }
}

__global__ __launch_bounds__(256, 3) void attn_kernel(
    const unsigned short* __restrict__ Q,
    const unsigned short* __restrict__ K,
    const unsigned short* __restrict__ Vt,
    unsigned short* __restrict__ O) {
  __shared__ unsigned short Ks[2][32 * 192];
  __shared__ unsigned short Vs[2][128 * 32];
  __shared__ unsigned short Ps[4][16 * 32];
  const int tid = threadIdx.x, lane = tid & 63, w = tid >> 6;
  const int wg = (int)blockIdx.x;
  const int lin = (wg & 7) * 128 + (wg >> 3);
  const int h = lin >> 5;
  const int qt = 31 - (lin & 31);
  const int qr0 = qt * 64 + w * 16;
  const int lg = lane >> 4, lm = lane & 15, lm7 = lane & 7;
  const unsigned short* Qh = Q + (size_t)h * S_LEN * QKD;
  const unsigned short* Kh = K + (size_t)h * S_LEN * QKD;
  const unsigned short* Vh = Vt + (size_t)h * 128 * S_LEN;

  bf16x8 qf[6];
#pragma unroll
  for (int f = 0; f < 6; ++f)
    qf[f] = *reinterpret_cast<const bf16x8*>(
        Qh + (size_t)(qr0 + lm) * QKD + f * 32 + lg * 8);

  f32x4 o[8] = {};
  float l[4] = {};

  auto STAGE = [&](int b, int kp) {
#pragma unroll
    for (int i = 0; i < 3; ++i) {
      int fb = (w * 3 + i) * 64 + lane;
      int row = fb / 24;
      int blk = fb - row * 24;
      int gb = (blk & ~7) | ((blk ^ row) & 7);
      stage16(Kh + (size_t)(kp + row) * QKD + gb * 8, &Ks[b][(w * 3 + i) * 512], lane);
    }
#pragma unroll
    for (int i = 0; i < 2; ++i) {
      int fb = (w * 2 + i) * 64 + lane;
      int row = fb >> 2;
      int blk = fb & 3;
      stage16(Vh + (size_t)row * S_LEN + kp + blk * 8, &Vs[b][(w * 2 + i) * 512], lane);
    }
  };

  const int ntiles = (qt + 1) * 2;
  STAGE(0, 0);
  __syncthreads();
  int buf = 0;
  for (int ti = 0; ti < ntiles; ++ti) {
    const int kp = ti * 32;
    if (ti + 1 < ntiles) STAGE(buf ^ 1, kp + 32);
    if (kp <= qr0 + 15) {
      f32x4 sc[2] = {};
      __builtin_amdgcn_s_setprio(1);
#pragma unroll
      for (int f = 0; f < 6; ++f)
#pragma unroll
        for (int c = 0; c < 2; ++c) {
          int blk = f * 4 + lg;
          int sb = (blk & ~7) | ((blk ^ lm7) & 7);
          bf16x8 kf = *reinterpret_cast<const bf16x8*>(&Ks[buf][(c * 16 + lm) * 192 + sb * 8]);
          sc[c] = __builtin_amdgcn_mfma_f32_16x16x32_bf16(qf[f], kf, sc[c], 0, 0, 0);
        }
      __builtin_amdgcn_s_setprio(0);
      const int rb = qr0 + lg * 4;
#pragma unroll
      for (int r = 0; r < 4; ++r) {
        const int row = rb + r;
        float v0 = fmaf(sc[0][r], SC2F, -32.f); if (kp + lm > row) v0 = -1e9f;
        float v1 = fmaf(sc[1][r], SC2F, -32.f); if (kp + 16 + lm > row) v1 = -1e9f;
        float p0 = ex2(v0), p1 = ex2(v1);
        l[r] += p0 + p1;
        int pr = lg * 4 + r;
        int s3 = pr & 3;
        int b0 = lm >> 3;
        unsigned short* pp = &Ps[w][pr * 32];
        pp[((b0 ^ s3) << 3) + lm7] = f2bf(p0);
        pp[(((2 + b0) ^ s3) << 3) + lm7] = f2bf(p1);
      }
      bf16x8 pa = *reinterpret_cast<const bf16x8*>(
          &Ps[w][lm * 32 + ((lg ^ (lm & 3)) << 3)]);
      __builtin_amdgcn_s_setprio(1);
#pragma unroll
      for (int d = 0; d < 8; ++d) {
        bf16x8 vf = *reinterpret_cast<const bf16x8*>(&Vs[buf][(d * 16 + lm) * 32 + lg * 8]);
        o[d] = __builtin_amdgcn_mfma_f32_16x16x32_bf16(pa, vf, o[d], 0, 0, 0);
      }
      __builtin_amdgcn_s_setprio(0);
    }
    __syncthreads();
    buf ^= 1;
  }
#pragma unroll
  for (int r = 0; r < 4; ++r) {
    float t = l[r];
#pragma unroll
    for (int off = 1; off < 16; off <<= 1) t += __shfl_xor(t, off, 16);
    float inv = 1.0f / t;
    int row = qr0 + lg * 4 + r;
#pragma unroll
    for (int d = 0; d < 8; ++d)
      O[(size_t)row * 4096 + h * 128 + d * 16 + lm] = f2bf(o[d][r] * inv);
  }
}

extern "C" void kernel_launch(void* const* d_in, const int* in_sizes, int n_in,
                              void* d_out, int out_size, void* d_ws, size_t ws_size,
                              hipStream_t stream) {
  const float* hs = (const float*)d_in[0];
  const float* freqs = (const float*)d_in[1];
  const float* q_a_w = (const float*)d_in[2];
  const float* q_a_ln = (const float*)d_in[3];
  const float* q_b_w = (const float*)d_in[4];
  const float* kv_a_w = (const float*)d_in[5];
  const float* kv_a_ln = (const float*)d_in[6];
  const float* kv_b_w = (const float*)d_in[7];
  const float* o_w = (const float*)d_in[8];
  float* out = (float*)d_out;

  char* ws = (char*)d_ws;
  unsigned short* hs_bf = (unsigned short*)(ws + 33554432);
  unsigned short* attnb = (unsigned short*)(ws + 33554432);
  float* qa_part = (float*)(ws + 50331648);
  unsigned short* kv_bf = (unsigned short*)(ws + 50331648);
  float* ckv_part = (float*)(ws + 100663296);
  unsigned short* Qb = (unsigned short*)(ws + 100663296);
  unsigned short* qa_bf = (unsigned short*)(ws + 138412032);
  unsigned short* ckv_bf = (unsigned short*)(ws + 144703488);
  float* rotf = (float*)(ws + 146800640);
  unsigned short* qfullb = (unsigned short*)(ws + 147324928);
  unsigned short* Kb = (unsigned short*)(ws + 147324928);
  unsigned short* Vt = (unsigned short*)(ws + 172490752);

  dim3 blk(256);
  // hs -> bf16 (only remaining cvt; weights converted inside GEMM staging)
  {
    int n8 = (int)((size_t)S_LEN * HDIM / 8);
    cvt_kernel<<<(n8 + 255) / 256, blk, 0, stream>>>(hs, hs_bf, n8);
  }
  gemm_bf<false, true><<<dim3(RQ_ / 128, S_LEN / 128, 4), blk, 0, stream>>>(
      hs_bf, HDIM, q_a_w, HDIM, qa_part, RQ_, RQ_, HDIM / 4);
  gemm_bf<false, true><<<dim3((CKV_W + 127) / 128, S_LEN / 128, 8), blk, 0, stream>>>(
      hs_bf, HDIM, kv_a_w, HDIM, ckv_part, CKV_W, CKV_W, HDIM / 8);
  rms_sum_q<<<S_LEN, blk, 0, stream>>>(qa_part, q_a_ln, qa_bf);
  rms_sum_kv<<<S_LEN, blk, 0, stream>>>(ckv_part, kv_a_ln, ckv_bf, rotf);
  gemm_bf<true, false><<<dim3(QFW / 128, S_LEN / 128), blk, 0, stream>>>(
      qa_bf, RQ_, q_b_w, RQ_, qfullb, QFW, QFW, RQ_);
  gemm_bf<true, false><<<dim3(KVW / 128, S_LEN / 128), blk, 0, stream>>>(
      ckv_bf, 512, kv_b_w, 512, kv_bf, KVW, KVW, 512);
  build_q_kernel<<<(NHEAD * S_LEN * 96 + 255) / 256, blk, 0, stream>>>(qfullb, freqs, Qb);
  build_k_kernel<<<(NHEAD * S_LEN * 96 + 255) / 256, blk, 0, stream>>>(kv_bf, rotf, freqs, Kb);
  build_vt_kernel<<<dim3(S_LEN / 32, NHEAD), blk, 0, stream>>>(kv_bf, Vt);
  attn_kernel<<<dim3(1024), blk, 0, stream>>>(Qb, Kb, Vt, attnb);
  gemm_bf<false, false><<<dim3(HDIM / 128, S_LEN / 128), blk, 0, stream>>>(
      attnb, HDIM, o_w, HDIM, out, HDIM, HDIM, HDIM);
}

// Round 18
// 551.279 us; speedup vs baseline: 1.3595x; 1.3595x over previous
//
#include <hip/hip_runtime.h>
#define S_LEN 2048
#define HDIM 4096
#define NHEAD 32
#define QKD 192
#define RQ_ 1536
#define CKV_W 576
#define KVW 8192
#define QFW 6144
#define SC2F 0.1041216313667742f

typedef float f32x4 __attribute__((ext_vector_type(4)));
typedef __bf16 bf16x8 __attribute__((ext_vector_type(8)));

__device__ __forceinline__ unsigned short f2bf(float f) {
  unsigned int u = __float_as_uint(f);
  u += 0x7fffu + ((u >> 16) & 1u);
  return (unsigned short)(u >> 16);
}
__device__ __forceinline__ float b2f(unsigned short u) {
  return __uint_as_float((unsigned int)u << 16);
}
__device__ __forceinline__ float ex2(float x) { return exp2f(x); }

__device__ __forceinline__ void stage16(const void* g, void* lds_base, int lane) {
  __builtin_amdgcn_global_load_lds(
      (const __attribute__((address_space(1))) unsigned int*)g,
      (__attribute__((address_space(3))) unsigned int*)lds_base, 16, 0, 0);
}

__global__ __launch_bounds__(256) void cvt_kernel(
    const float* __restrict__ in, unsigned short* __restrict__ out, int n8) {
  int i = blockIdx.x * 256 + threadIdx.x;
  if (i >= n8) return;
  const float4* p = reinterpret_cast<const float4*>(in) + (size_t)i * 2;
  float4 a = p[0], b = p[1];
  unsigned long long lo = (unsigned long long)f2bf(a.x) | ((unsigned long long)f2bf(a.y) << 16)
      | ((unsigned long long)f2bf(a.z) << 32) | ((unsigned long long)f2bf(a.w) << 48);
  unsigned long long hi = (unsigned long long)f2bf(b.x) | ((unsigned long long)f2bf(b.y) << 16)
      | ((unsigned long long)f2bf(b.z) << 32) | ((unsigned long long)f2bf(b.w) << 48);
  unsigned long long* q = reinterpret_cast<unsigned long long*>(out) + (size_t)i * 2;
  q[0] = lo; q[1] = hi;
}

// BK=32 2-phase dbuf 128x128 GEMM, M-fast XCD decode (B-panel L2-resident).
template<bool BF16OUT, bool SPLITK>
__global__ __launch_bounds__(256) void gemm_bf(
    const unsigned short* __restrict__ A, int lda,
    const unsigned short* __restrict__ B, int ldb,
    void* __restrict__ Cv, int ldc, int N, int K) {
  __shared__ unsigned short As[2][4][128][8];
  __shared__ unsigned short Bs[2][4][128][8];
  const int tid = threadIdx.x, lane = tid & 63, w = tid >> 6;
  const int gx = (int)gridDim.x, gy = (int)gridDim.y;
  const int nwg = gx * gy;
  int lin = (int)blockIdx.y * gx + (int)blockIdx.x;
  if ((nwg & 7) == 0) lin = (lin & 7) * (nwg >> 3) + (lin >> 3);
  const int bm = (lin % gy) * 128, bn = (lin / gy) * 128;
  const int koff = SPLITK ? (int)blockIdx.z * K : 0;
  const int wr = (w >> 1) * 64, wc = (w & 1) * 64;
  const int lg = lane >> 4, lm = lane & 15;
  f32x4 acc[4][4] = {};
  const int arow = bm + lane;
  int brow = bn + lane; if (brow >= N) brow = N - 1;

  auto STAGE = [&](int buf, int k0) {
#pragma unroll
    for (int i = 0; i < 2; ++i) {
      stage16(A + (size_t)(arow + i * 64) * lda + koff + k0 + w * 8, &As[buf][w][i * 64][0], lane);
      int br2 = brow + i * 64; if (br2 >= N) br2 = N - 1;
      stage16(B + (size_t)br2 * ldb + koff + k0 + w * 8, &Bs[buf][w][i * 64][0], lane);
    }
  };
  STAGE(0, 0);
  __syncthreads();
  int cur = 0;
  for (int k0 = 0; k0 < K; k0 += 32) {
    if (k0 + 32 < K) STAGE(cur ^ 1, k0 + 32);
    bf16x8 af[4], bf[4];
#pragma unroll
    for (int i = 0; i < 4; ++i)
      af[i] = *reinterpret_cast<const bf16x8*>(&As[cur][lg][wr + i * 16 + lm][0]);
#pragma unroll
    for (int j = 0; j < 4; ++j)
      bf[j] = *reinterpret_cast<const bf16x8*>(&Bs[cur][lg][wc + j * 16 + lm][0]);
    __builtin_amdgcn_s_setprio(1);
#pragma unroll
    for (int i = 0; i < 4; ++i)
#pragma unroll
      for (int j = 0; j < 4; ++j)
        acc[i][j] = __builtin_amdgcn_mfma_f32_16x16x32_bf16(af[i], bf[j], acc[i][j], 0, 0, 0);
    __builtin_amdgcn_s_setprio(0);
    __syncthreads();
    cur ^= 1;
  }
  size_t zoff = SPLITK ? (size_t)blockIdx.z * S_LEN * N : 0;
#pragma unroll
  for (int i = 0; i < 4; ++i)
#pragma unroll
    for (int j = 0; j < 4; ++j)
#pragma unroll
      for (int r = 0; r < 4; ++r) {
        int row = bm + wr + i * 16 + lg * 4 + r;
        int col = bn + wc + j * 16 + lm;
        if (col < N) {
          if constexpr (BF16OUT)
            ((unsigned short*)Cv)[(size_t)row * ldc + col] = f2bf(acc[i][j][r]);
          else
            ((float*)Cv)[zoff + (size_t)row * ldc + col] = acc[i][j][r];
        }
      }
}

__global__ __launch_bounds__(256) void rms_sum_q(
    const float* __restrict__ P, const float* __restrict__ w,
    unsigned short* __restrict__ y) {
  __shared__ float red[4];
  const int row = blockIdx.x, tid = threadIdx.x;
  const float* base = P + (size_t)row * RQ_;
  float x[6]; float ss = 0.f;
#pragma unroll
  for (int ii = 0; ii < 6; ++ii) {
    int j = tid + ii * 256;
    float v = 0.f;
#pragma unroll
    for (int z = 0; z < 4; ++z) v += base[(size_t)z * S_LEN * RQ_ + j];
    x[ii] = v; ss += v * v;
  }
#pragma unroll
  for (int off = 1; off < 64; off <<= 1) ss += __shfl_xor(ss, off, 64);
  if ((tid & 63) == 0) red[tid >> 6] = ss;
  __syncthreads();
  float scale = rsqrtf((red[0] + red[1] + red[2] + red[3]) / (float)RQ_ + 1e-6f);
  unsigned short* q = y + (size_t)row * RQ_;
#pragma unroll
  for (int ii = 0; ii < 6; ++ii) {
    int j = tid + ii * 256;
    q[j] = f2bf(x[ii] * scale * w[j]);
  }
}

__global__ __launch_bounds__(256) void rms_sum_kv(
    const float* __restrict__ P, const float* __restrict__ w,
    unsigned short* __restrict__ y, float* __restrict__ rotf) {
  __shared__ float red[4];
  const int row = blockIdx.x, tid = threadIdx.x;
  const float* base = P + (size_t)row * CKV_W;
  float x0 = 0.f, x1 = 0.f, x2 = 0.f;
#pragma unroll
  for (int z = 0; z < 8; ++z) {
    const float* b = base + (size_t)z * S_LEN * CKV_W;
    x0 += b[tid]; x1 += b[tid + 256];
    if (tid < 64) x2 += b[tid + 512];
  }
  float ss = x0 * x0 + x1 * x1;
#pragma unroll
  for (int off = 1; off < 64; off <<= 1) ss += __shfl_xor(ss, off, 64);
  if ((tid & 63) == 0) red[tid >> 6] = ss;
  __syncthreads();
  float scale = rsqrtf((red[0] + red[1] + red[2] + red[3]) / 512.0f + 1e-6f);
  unsigned short* q = y + (size_t)row * 512;
  q[tid] = f2bf(x0 * scale * w[tid]);
  q[tid + 256] = f2bf(x1 * scale * w[tid + 256]);
  if (tid < 64) rotf[(size_t)row * 64 + tid] = x2;
}

__global__ __launch_bounds__(256) void build_q_kernel(
    const unsigned short* __restrict__ qf, const float* __restrict__ freqs,
    unsigned short* __restrict__ Q) {
  int idx = blockIdx.x * 256 + threadIdx.x;
  if (idx >= NHEAD * S_LEN * 96) return;
  int j = idx % 96, s = (idx / 96) % S_LEN, h = idx / (96 * S_LEN);
  const unsigned short* src = qf + (size_t)s * QFW + h * QKD;
  unsigned int pk;
  if (j < 64) {
    pk = *reinterpret_cast<const unsigned int*>(&src[2 * j]);
  } else {
    int r = j - 64;
    float xr = b2f(src[128 + 2 * r]), xi = b2f(src[128 + 2 * r + 1]);
    float f = freqs[(size_t)s * 32 + r];
    float c = cosf(f), sn = sinf(f);
    pk = (unsigned int)f2bf(xr * c - xi * sn) | ((unsigned int)f2bf(xr * sn + xi * c) << 16);
  }
  *reinterpret_cast<unsigned int*>(Q + ((size_t)(h * S_LEN + s) * QKD + 2 * j)) = pk;
}

__global__ __launch_bounds__(256) void build_k_kernel(
    const unsigned short* __restrict__ kv, const float* __restrict__ rotf,
    const float* __restrict__ freqs, unsigned short* __restrict__ K) {
  int idx = blockIdx.x * 256 + threadIdx.x;
  if (idx >= NHEAD * S_LEN * 96) return;
  int j = idx % 96, s = (idx / 96) % S_LEN, h = idx / (96 * S_LEN);
  unsigned int pk;
  if (j < 64) {
    pk = *reinterpret_cast<const unsigned int*>(&kv[(size_t)s * KVW + h * 256 + 2 * j]);
  } else {
    int r = j - 64;
    float xr = rotf[(size_t)s * 64 + 2 * r];
    float xi = rotf[(size_t)s * 64 + 2 * r + 1];
    float f = freqs[(size_t)s * 32 + r];
    float c = cosf(f), sn = sinf(f);
    pk = (unsigned int)f2bf(xr * c - xi * sn) | ((unsigned int)f2bf(xr * sn + xi * c) << 16);
  }
  *reinterpret_cast<unsigned int*>(K + ((size_t)(h * S_LEN + s) * QKD + 2 * j)) = pk;
}

__global__ __launch_bounds__(256) void build_vt_kernel(
    const unsigned short* __restrict__ kv, unsigned short* __restrict__ Vt) {
  __shared__ unsigned short T[128][33];
  const int tid = threadIdx.x;
  const int h = blockIdx.y, s0 = blockIdx.x * 32;
#pragma unroll
  for (int p = 0; p < 16; ++p) {
    int i = p * 256 + tid;
    int d = i & 127, sr = i >> 7;
    T[d][sr] = kv[(size_t)(s0 + sr) * KVW + h * 256 + 128 + d];
  }
  __syncthreads();
#pragma unroll
  for (int p = 0; p < 8; ++p) {
    int i = p * 256 + tid;
    int d = i >> 4, sp = (i & 15) * 2;
    unsigned int pk = (unsigned int)T[d][sp] | ((unsigned int)T[d][sp + 1] << 16);
    *reinterpret_cast<unsigned int*>(Vt + (size_t)(h * 128 + d) * S_LEN + s0 + sp) = pk;
  }
}

// QBLK=64 (4 waves x 16 q-rows), KVB=32, dbuf staging, 44 KB LDS, 3 blk/CU.
__global__ __launch_bounds__(256, 3) void attn_kernel(
    const unsigned short* __restrict__ Q,
    const unsigned short* __restrict__ K,
    const unsigned short* __restrict__ Vt,
    unsigned short* __restrict__ O) {
  __shared__ unsigned short Ks[2][32 * 192];
  __shared__ unsigned short Vs[2][128 * 32];
  __shared__ unsigned short Ps[4][16 * 32];
  const int tid = threadIdx.x, lane = tid & 63, w = tid >> 6;
  const int wg = (int)blockIdx.x;
  const int lin = (wg & 7) * 128 + (wg >> 3);
  const int h = lin >> 5;
  const int qt = 31 - (lin & 31);
  const int qr0 = qt * 64 + w * 16;
  const int lg = lane >> 4, lm = lane & 15, lm7 = lane & 7;
  const unsigned short* Qh = Q + (size_t)h * S_LEN * QKD;
  const unsigned short* Kh = K + (size_t)h * S_LEN * QKD;
  const unsigned short* Vh = Vt + (size_t)h * 128 * S_LEN;

  bf16x8 qf[6];
#pragma unroll
  for (int f = 0; f < 6; ++f)
    qf[f] = *reinterpret_cast<const bf16x8*>(
        Qh + (size_t)(qr0 + lm) * QKD + f * 32 + lg * 8);

  f32x4 o[8] = {};
  float l[4] = {};

  auto STAGE = [&](int b, int kp) {
#pragma unroll
    for (int i = 0; i < 3; ++i) {
      int fb = (w * 3 + i) * 64 + lane;
      int row = fb / 24;
      int blk = fb - row * 24;
      int gb = (blk & ~7) | ((blk ^ row) & 7);
      stage16(Kh + (size_t)(kp + row) * QKD + gb * 8, &Ks[b][(w * 3 + i) * 512], lane);
    }
#pragma unroll
    for (int i = 0; i < 2; ++i) {
      int fb = (w * 2 + i) * 64 + lane;
      int row = fb >> 2;
      int blk = fb & 3;
      stage16(Vh + (size_t)row * S_LEN + kp + blk * 8, &Vs[b][(w * 2 + i) * 512], lane);
    }
  };

  const int ntiles = (qt + 1) * 2;
  STAGE(0, 0);
  __syncthreads();
  int buf = 0;
  for (int ti = 0; ti < ntiles; ++ti) {
    const int kp = ti * 32;
    if (ti + 1 < ntiles) STAGE(buf ^ 1, kp + 32);
    if (kp <= qr0 + 15) {
      f32x4 sc[2] = {};
      __builtin_amdgcn_s_setprio(1);
#pragma unroll
      for (int f = 0; f < 6; ++f)
#pragma unroll
        for (int c = 0; c < 2; ++c) {
          int blk = f * 4 + lg;
          int sb = (blk & ~7) | ((blk ^ lm7) & 7);
          bf16x8 kf = *reinterpret_cast<const bf16x8*>(&Ks[buf][(c * 16 + lm) * 192 + sb * 8]);
          sc[c] = __builtin_amdgcn_mfma_f32_16x16x32_bf16(qf[f], kf, sc[c], 0, 0, 0);
        }
      __builtin_amdgcn_s_setprio(0);
      const int rb = qr0 + lg * 4;
#pragma unroll
      for (int r = 0; r < 4; ++r) {
        const int row = rb + r;
        float v0 = fmaf(sc[0][r], SC2F, -32.f); if (kp + lm > row) v0 = -1e9f;
        float v1 = fmaf(sc[1][r], SC2F, -32.f); if (kp + 16 + lm > row) v1 = -1e9f;
        float p0 = ex2(v0), p1 = ex2(v1);
        l[r] += p0 + p1;
        int pr = lg * 4 + r;
        int s3 = pr & 3;
        int b0 = lm >> 3;
        unsigned short* pp = &Ps[w][pr * 32];
        pp[((b0 ^ s3) << 3) + lm7] = f2bf(p0);
        pp[(((2 + b0) ^ s3) << 3) + lm7] = f2bf(p1);
      }
      bf16x8 pa = *reinterpret_cast<const bf16x8*>(
          &Ps[w][lm * 32 + ((lg ^ (lm & 3)) << 3)]);
      __builtin_amdgcn_s_setprio(1);
#pragma unroll
      for (int d = 0; d < 8; ++d) {
        bf16x8 vf = *reinterpret_cast<const bf16x8*>(&Vs[buf][(d * 16 + lm) * 32 + lg * 8]);
        o[d] = __builtin_amdgcn_mfma_f32_16x16x32_bf16(pa, vf, o[d], 0, 0, 0);
      }
      __builtin_amdgcn_s_setprio(0);
    }
    __syncthreads();
    buf ^= 1;
  }
#pragma unroll
  for (int r = 0; r < 4; ++r) {
    float t = l[r];
#pragma unroll
    for (int off = 1; off < 16; off <<= 1) t += __shfl_xor(t, off, 16);
    float inv = 1.0f / t;
    int row = qr0 + lg * 4 + r;
#pragma unroll
    for (int d = 0; d < 8; ++d)
      O[(size_t)row * 4096 + h * 128 + d * 16 + lm] = f2bf(o[d][r] * inv);
  }
}

extern "C" void kernel_launch(void* const* d_in, const int* in_sizes, int n_in,
                              void* d_out, int out_size, void* d_ws, size_t ws_size,
                              hipStream_t stream) {
  const float* hs = (const float*)d_in[0];
  const float* freqs = (const float*)d_in[1];
  const float* q_a_w = (const float*)d_in[2];
  const float* q_a_ln = (const float*)d_in[3];
  const float* q_b_w = (const float*)d_in[4];
  const float* kv_a_w = (const float*)d_in[5];
  const float* kv_a_ln = (const float*)d_in[6];
  const float* kv_b_w = (const float*)d_in[7];
  const float* o_w = (const float*)d_in[8];
  float* out = (float*)d_out;

  char* ws = (char*)d_ws;
  unsigned short* wslot = (unsigned short*)(ws + 0);
  unsigned short* hs_bf = (unsigned short*)(ws + 33554432);
  unsigned short* attnb = (unsigned short*)(ws + 33554432);
  float* qa_part = (float*)(ws + 50331648);
  unsigned short* kv_bf = (unsigned short*)(ws + 50331648);
  float* ckv_part = (float*)(ws + 100663296);
  unsigned short* Qb = (unsigned short*)(ws + 100663296);
  unsigned short* qa_bf = (unsigned short*)(ws + 138412032);
  unsigned short* ckv_bf = (unsigned short*)(ws + 144703488);
  float* rotf = (float*)(ws + 146800640);
  unsigned short* qfullb = (unsigned short*)(ws + 147324928);
  unsigned short* Kb = (unsigned short*)(ws + 147324928);
  unsigned short* Vt = (unsigned short*)(ws + 172490752);

  dim3 blk(256);
  auto cvt = [&](const float* src, unsigned short* dst, size_t n) {
    int n8 = (int)(n / 8);
    cvt_kernel<<<(n8 + 255) / 256, blk, 0, stream>>>(src, dst, n8);
  };

  cvt(hs, hs_bf, (size_t)S_LEN * HDIM);
  cvt(q_a_w, wslot, (size_t)RQ_ * HDIM);
  gemm_bf<false, true><<<dim3(RQ_ / 128, S_LEN / 128, 4), blk, 0, stream>>>(
      hs_bf, HDIM, wslot, HDIM, qa_part, RQ_, RQ_, HDIM / 4);
  cvt(kv_a_w, wslot, (size_t)CKV_W * HDIM);
  gemm_bf<false, true><<<dim3((CKV_W + 127) / 128, S_LEN / 128, 8), blk, 0, stream>>>(
      hs_bf, HDIM, wslot, HDIM, ckv_part, CKV_W, CKV_W, HDIM / 8);
  rms_sum_q<<<S_LEN, blk, 0, stream>>>(qa_part, q_a_ln, qa_bf);
  rms_sum_kv<<<S_LEN, blk, 0, stream>>>(ckv_part, kv_a_ln, ckv_bf, rotf);
  cvt(q_b_w, wslot, (size_t)QFW * RQ_);
  gemm_bf<true, false><<<dim3(QFW / 128, S_LEN / 128), blk, 0, stream>>>(
      qa_bf, RQ_, wslot, RQ_, qfullb, QFW, QFW, RQ_);
  cvt(kv_b_w, wslot, (size_t)KVW * 512);
  gemm_bf<true, false><<<dim3(KVW / 128, S_LEN / 128), blk, 0, stream>>>(
      ckv_bf, 512, wslot, 512, kv_bf, KVW, KVW, 512);
  build_q_kernel<<<(NHEAD * S_LEN * 96 + 255) / 256, blk, 0, stream>>>(qfullb, freqs, Qb);
  build_k_kernel<<<(NHEAD * S_LEN * 96 + 255) / 256, blk, 0, stream>>>(kv_bf, rotf, freqs, Kb);
  build_vt_kernel<<<dim3(S_LEN / 32, NHEAD), blk, 0, stream>>>(kv_bf, Vt);
  attn_kernel<<<dim3(1024), blk, 0, stream>>>(Qb, Kb, Vt, attnb);
  cvt(o_w, wslot, (size_t)HDIM * HDIM);
  gemm_bf<false, false><<<dim3(HDIM / 128, S_LEN / 128), blk, 0, stream>>>(
      attnb, HDIM, wslot, HDIM, out, HDIM, HDIM, HDIM);
}

// Round 19
// 523.682 us; speedup vs baseline: 1.4311x; 1.0527x over previous
//
#include <hip/hip_runtime.h>
#define S_LEN 2048
#define HDIM 4096
#define NHEAD 32
#define QKD 192
#define RQ_ 1536
#define CKV_W 576
#define KVW 8192
#define QFW 6144
#define SC2F 0.1041216313667742f

typedef float f32x4 __attribute__((ext_vector_type(4)));
typedef __bf16 bf16x8 __attribute__((ext_vector_type(8)));

__device__ __forceinline__ unsigned short f2bf(float f) {
  unsigned int u = __float_as_uint(f);
  u += 0x7fffu + ((u >> 16) & 1u);
  return (unsigned short)(u >> 16);
}
__device__ __forceinline__ float b2f(unsigned short u) {
  return __uint_as_float((unsigned int)u << 16);
}
__device__ __forceinline__ float ex2(float x) { return exp2f(x); }

__device__ __forceinline__ void stage16(const void* g, void* lds_base, int lane) {
  __builtin_amdgcn_global_load_lds(
      (const __attribute__((address_space(1))) unsigned int*)g,
      (__attribute__((address_space(3))) unsigned int*)lds_base, 16, 0, 0);
}

__global__ __launch_bounds__(256) void cvt_kernel(
    const float* __restrict__ in, unsigned short* __restrict__ out, int n8) {
  int i = blockIdx.x * 256 + threadIdx.x;
  if (i >= n8) return;
  const float4* p = reinterpret_cast<const float4*>(in) + (size_t)i * 2;
  float4 a = p[0], b = p[1];
  unsigned long long lo = (unsigned long long)f2bf(a.x) | ((unsigned long long)f2bf(a.y) << 16)
      | ((unsigned long long)f2bf(a.z) << 32) | ((unsigned long long)f2bf(a.w) << 48);
  unsigned long long hi = (unsigned long long)f2bf(b.x) | ((unsigned long long)f2bf(b.y) << 16)
      | ((unsigned long long)f2bf(b.z) << 32) | ((unsigned long long)f2bf(b.w) << 48);
  unsigned long long* q = reinterpret_cast<unsigned long long*>(out) + (size_t)i * 2;
  q[0] = lo; q[1] = hi;
}

// BK=32 2-phase dbuf 128x128 GEMM, M-fast XCD decode.
// VSCAT: V-half 128-col tiles (bn&255)>=128 scatter transposed into VtOut.
template<bool BF16OUT, bool SPLITK, bool VSCAT>
__global__ __launch_bounds__(256) void gemm_bf(
    const unsigned short* __restrict__ A, int lda,
    const unsigned short* __restrict__ B, int ldb,
    void* __restrict__ Cv, int ldc, int N, int K,
    unsigned short* __restrict__ VtOut) {
  __shared__ unsigned short As[2][4][128][8];
  __shared__ unsigned short Bs[2][4][128][8];
  const int tid = threadIdx.x, lane = tid & 63, w = tid >> 6;
  const int gx = (int)gridDim.x, gy = (int)gridDim.y;
  const int nwg = gx * gy;
  int lin = (int)blockIdx.y * gx + (int)blockIdx.x;
  if ((nwg & 7) == 0) lin = (lin & 7) * (nwg >> 3) + (lin >> 3);
  const int bm = (lin % gy) * 128, bn = (lin / gy) * 128;
  const int koff = SPLITK ? (int)blockIdx.z * K : 0;
  const int wr = (w >> 1) * 64, wc = (w & 1) * 64;
  const int lg = lane >> 4, lm = lane & 15;
  f32x4 acc[4][4] = {};
  const int arow = bm + lane;
  int brow = bn + lane; if (brow >= N) brow = N - 1;

  auto STAGE = [&](int buf, int k0) {
#pragma unroll
    for (int i = 0; i < 2; ++i) {
      stage16(A + (size_t)(arow + i * 64) * lda + koff + k0 + w * 8, &As[buf][w][i * 64][0], lane);
      int br2 = brow + i * 64; if (br2 >= N) br2 = N - 1;
      stage16(B + (size_t)br2 * ldb + koff + k0 + w * 8, &Bs[buf][w][i * 64][0], lane);
    }
  };
  STAGE(0, 0);
  __syncthreads();
  int cur = 0;
  for (int k0 = 0; k0 < K; k0 += 32) {
    if (k0 + 32 < K) STAGE(cur ^ 1, k0 + 32);
    bf16x8 af[4], bf[4];
#pragma unroll
    for (int i = 0; i < 4; ++i)
      af[i] = *reinterpret_cast<const bf16x8*>(&As[cur][lg][wr + i * 16 + lm][0]);
#pragma unroll
    for (int j = 0; j < 4; ++j)
      bf[j] = *reinterpret_cast<const bf16x8*>(&Bs[cur][lg][wc + j * 16 + lm][0]);
    __builtin_amdgcn_s_setprio(1);
#pragma unroll
    for (int i = 0; i < 4; ++i)
#pragma unroll
      for (int j = 0; j < 4; ++j)
        acc[i][j] = __builtin_amdgcn_mfma_f32_16x16x32_bf16(af[i], bf[j], acc[i][j], 0, 0, 0);
    __builtin_amdgcn_s_setprio(0);
    __syncthreads();
    cur ^= 1;
  }

  if constexpr (VSCAT) {
    if (bn & 128) {   // V-half tile: write transposed into Vt[h][d][s]
      const int h2 = bn >> 8;
#pragma unroll
      for (int i = 0; i < 4; ++i)
#pragma unroll
        for (int j = 0; j < 4; ++j) {
          int d = wc + j * 16 + lm;        // 0..127
          unsigned long long pk =
                (unsigned long long)f2bf(acc[i][j][0])
              | ((unsigned long long)f2bf(acc[i][j][1]) << 16)
              | ((unsigned long long)f2bf(acc[i][j][2]) << 32)
              | ((unsigned long long)f2bf(acc[i][j][3]) << 48);
          *reinterpret_cast<unsigned long long*>(
              VtOut + (size_t)(h2 * 128 + d) * S_LEN + bm + wr + i * 16 + lg * 4) = pk;
        }
      return;
    }
  }

  size_t zoff = SPLITK ? (size_t)blockIdx.z * S_LEN * N : 0;
#pragma unroll
  for (int i = 0; i < 4; ++i)
#pragma unroll
    for (int j = 0; j < 4; ++j)
#pragma unroll
      for (int r = 0; r < 4; ++r) {
        int row = bm + wr + i * 16 + lg * 4 + r;
        int col = bn + wc + j * 16 + lm;
        if (col < N) {
          if constexpr (BF16OUT)
            ((unsigned short*)Cv)[(size_t)row * ldc + col] = f2bf(acc[i][j][r]);
          else
            ((float*)Cv)[zoff + (size_t)row * ldc + col] = acc[i][j][r];
        }
      }
}

__global__ __launch_bounds__(256) void rms_sum_q(
    const float* __restrict__ P, const float* __restrict__ w,
    unsigned short* __restrict__ y) {
  __shared__ float red[4];
  const int row = blockIdx.x, tid = threadIdx.x;
  const float* base = P + (size_t)row * RQ_;
  float x[6]; float ss = 0.f;
#pragma unroll
  for (int ii = 0; ii < 6; ++ii) {
    int j = tid + ii * 256;
    float v = 0.f;
#pragma unroll
    for (int z = 0; z < 4; ++z) v += base[(size_t)z * S_LEN * RQ_ + j];
    x[ii] = v; ss += v * v;
  }
#pragma unroll
  for (int off = 1; off < 64; off <<= 1) ss += __shfl_xor(ss, off, 64);
  if ((tid & 63) == 0) red[tid >> 6] = ss;
  __syncthreads();
  float scale = rsqrtf((red[0] + red[1] + red[2] + red[3]) / (float)RQ_ + 1e-6f);
  unsigned short* q = y + (size_t)row * RQ_;
#pragma unroll
  for (int ii = 0; ii < 6; ++ii) {
    int j = tid + ii * 256;
    q[j] = f2bf(x[ii] * scale * w[j]);
  }
}

__global__ __launch_bounds__(256) void rms_sum_kv(
    const float* __restrict__ P, const float* __restrict__ w,
    unsigned short* __restrict__ y, float* __restrict__ rotf) {
  __shared__ float red[4];
  const int row = blockIdx.x, tid = threadIdx.x;
  const float* base = P + (size_t)row * CKV_W;
  float x0 = 0.f, x1 = 0.f, x2 = 0.f;
#pragma unroll
  for (int z = 0; z < 8; ++z) {
    const float* b = base + (size_t)z * S_LEN * CKV_W;
    x0 += b[tid]; x1 += b[tid + 256];
    if (tid < 64) x2 += b[tid + 512];
  }
  float ss = x0 * x0 + x1 * x1;
#pragma unroll
  for (int off = 1; off < 64; off <<= 1) ss += __shfl_xor(ss, off, 64);
  if ((tid & 63) == 0) red[tid >> 6] = ss;
  __syncthreads();
  float scale = rsqrtf((red[0] + red[1] + red[2] + red[3]) / 512.0f + 1e-6f);
  unsigned short* q = y + (size_t)row * 512;
  q[tid] = f2bf(x0 * scale * w[tid]);
  q[tid + 256] = f2bf(x1 * scale * w[tid + 256]);
  if (tid < 64) rotf[(size_t)row * 64 + tid] = x2;
}

// In-place RoPE on qfullb cols [h*192+128, h*192+192)
__global__ __launch_bounds__(256) void rope_q_kernel(
    unsigned short* __restrict__ qf, const float* __restrict__ freqs) {
  int idx = blockIdx.x * 256 + threadIdx.x;        // NH*S*32
  if (idx >= NHEAD * S_LEN * 32) return;
  int r = idx & 31, s = (idx >> 5) & (S_LEN - 1), h = idx >> 16;
  unsigned short* p = qf + (size_t)s * QFW + h * QKD + 128 + 2 * r;
  float xr = b2f(p[0]), xi = b2f(p[1]);
  float f = freqs[(size_t)s * 32 + r];
  float c = cosf(f), sn = sinf(f);
  *reinterpret_cast<unsigned int*>(p) =
      (unsigned int)f2bf(xr * c - xi * sn) | ((unsigned int)f2bf(xr * sn + xi * c) << 16);
}

// rotf (f32 [S][64]) -> Kr (bf16 [S][64]) with RoPE
__global__ __launch_bounds__(256) void rope_k_kernel(
    const float* __restrict__ rotf, const float* __restrict__ freqs,
    unsigned short* __restrict__ Kr) {
  int idx = blockIdx.x * 256 + threadIdx.x;        // S*32
  if (idx >= S_LEN * 32) return;
  int r = idx & 31, s = idx >> 5;
  float xr = rotf[(size_t)s * 64 + 2 * r];
  float xi = rotf[(size_t)s * 64 + 2 * r + 1];
  float f = freqs[(size_t)s * 32 + r];
  float c = cosf(f), sn = sinf(f);
  *reinterpret_cast<unsigned int*>(Kr + (size_t)s * 64 + 2 * r) =
      (unsigned int)f2bf(xr * c - xi * sn) | ((unsigned int)f2bf(xr * sn + xi * c) << 16);
}

// QBLK=64 attn; Q from qfullb (stride 6144), K-pass from kv_bf (stride 8192),
// K-rope from shared Kr, V from Vt. Same LDS layout/read path as R18.
__global__ __launch_bounds__(256, 3) void attn_kernel(
    const unsigned short* __restrict__ Qf,
    const unsigned short* __restrict__ KV,
    const unsigned short* __restrict__ Kr,
    const unsigned short* __restrict__ Vt,
    unsigned short* __restrict__ O) {
  __shared__ unsigned short Ks[2][32 * 192];
  __shared__ unsigned short Vs[2][128 * 32];
  __shared__ unsigned short Ps[4][16 * 32];
  const int tid = threadIdx.x, lane = tid & 63, w = tid >> 6;
  const int wg = (int)blockIdx.x;
  const int lin = (wg & 7) * 128 + (wg >> 3);
  const int h = lin >> 5;
  const int qt = 31 - (lin & 31);
  const int qr0 = qt * 64 + w * 16;
  const int lg = lane >> 4, lm = lane & 15, lm7 = lane & 7;
  const unsigned short* Qh = Qf + h * QKD;
  const int hoff = h * 256;
  const unsigned short* Vh = Vt + (size_t)h * 128 * S_LEN;

  bf16x8 qf[6];
#pragma unroll
  for (int f = 0; f < 6; ++f)
    qf[f] = *reinterpret_cast<const bf16x8*>(
        Qh + (size_t)(qr0 + lm) * QFW + f * 32 + lg * 8);

  f32x4 o[8] = {};
  float l[4] = {};

  auto STAGE = [&](int b, int kp) {
#pragma unroll
    for (int i = 0; i < 3; ++i) {
      int fb = (w * 3 + i) * 64 + lane;
      int row = fb / 24;
      int blk = fb - row * 24;
      int gb = (blk & ~7) | ((blk ^ row) & 7);
      const unsigned short* src = (blk < 16)
          ? KV + (size_t)(kp + row) * KVW + hoff + gb * 8
          : Kr + (size_t)(kp + row) * 64 + (gb - 16) * 8;
      stage16(src, &Ks[b][(w * 3 + i) * 512], lane);
    }
#pragma unroll
    for (int i = 0; i < 2; ++i) {
      int fb = (w * 2 + i) * 64 + lane;
      int row = fb >> 2;
      int blk = fb & 3;
      stage16(Vh + (size_t)row * S_LEN + kp + blk * 8, &Vs[b][(w * 2 + i) * 512], lane);
    }
  };

  const int ntiles = (qt + 1) * 2;
  STAGE(0, 0);
  __syncthreads();
  int buf = 0;
  for (int ti = 0; ti < ntiles; ++ti) {
    const int kp = ti * 32;
    if (ti + 1 < ntiles) STAGE(buf ^ 1, kp + 32);
    if (kp <= qr0 + 15) {
      f32x4 sc[2] = {};
      __builtin_amdgcn_s_setprio(1);
#pragma unroll
      for (int f = 0; f < 6; ++f)
#pragma unroll
        for (int c = 0; c < 2; ++c) {
          int blk = f * 4 + lg;
          int sb = (blk & ~7) | ((blk ^ lm7) & 7);
          bf16x8 kf = *reinterpret_cast<const bf16x8*>(&Ks[buf][(c * 16 + lm) * 192 + sb * 8]);
          sc[c] = __builtin_amdgcn_mfma_f32_16x16x32_bf16(qf[f], kf, sc[c], 0, 0, 0);
        }
      __builtin_amdgcn_s_setprio(0);
      const int rb = qr0 + lg * 4;
#pragma unroll
      for (int r = 0; r < 4; ++r) {
        const int row = rb + r;
        float v0 = fmaf(sc[0][r], SC2F, -32.f); if (kp + lm > row) v0 = -1e9f;
        float v1 = fmaf(sc[1][r], SC2F, -32.f); if (kp + 16 + lm > row) v1 = -1e9f;
        float p0 = ex2(v0), p1 = ex2(v1);
        l[r] += p0 + p1;
        int pr = lg * 4 + r;
        int s3 = pr & 3;
        int b0 = lm >> 3;
        unsigned short* pp = &Ps[w][pr * 32];
        pp[((b0 ^ s3) << 3) + lm7] = f2bf(p0);
        pp[(((2 + b0) ^ s3) << 3) + lm7] = f2bf(p1);
      }
      bf16x8 pa = *reinterpret_cast<const bf16x8*>(
          &Ps[w][lm * 32 + ((lg ^ (lm & 3)) << 3)]);
      __builtin_amdgcn_s_setprio(1);
#pragma unroll
      for (int d = 0; d < 8; ++d) {
        bf16x8 vf = *reinterpret_cast<const bf16x8*>(&Vs[buf][(d * 16 + lm) * 32 + lg * 8]);
        o[d] = __builtin_amdgcn_mfma_f32_16x16x32_bf16(pa, vf, o[d], 0, 0, 0);
      }
      __builtin_amdgcn_s_setprio(0);
    }
    __syncthreads();
    buf ^= 1;
  }
#pragma unroll
  for (int r = 0; r < 4; ++r) {
    float t = l[r];
#pragma unroll
    for (int off = 1; off < 16; off <<= 1) t += __shfl_xor(t, off, 16);
    float inv = 1.0f / t;
    int row = qr0 + lg * 4 + r;
#pragma unroll
    for (int d = 0; d < 8; ++d)
      O[(size_t)row * 4096 + h * 128 + d * 16 + lm] = f2bf(o[d][r] * inv);
  }
}

extern "C" void kernel_launch(void* const* d_in, const int* in_sizes, int n_in,
                              void* d_out, int out_size, void* d_ws, size_t ws_size,
                              hipStream_t stream) {
  const float* hs = (const float*)d_in[0];
  const float* freqs = (const float*)d_in[1];
  const float* q_a_w = (const float*)d_in[2];
  const float* q_a_ln = (const float*)d_in[3];
  const float* q_b_w = (const float*)d_in[4];
  const float* kv_a_w = (const float*)d_in[5];
  const float* kv_a_ln = (const float*)d_in[6];
  const float* kv_b_w = (const float*)d_in[7];
  const float* o_w = (const float*)d_in[8];
  float* out = (float*)d_out;

  char* ws = (char*)d_ws;
  unsigned short* wslot = (unsigned short*)(ws + 0);           // 32 MiB
  unsigned short* hs_bf = (unsigned short*)(ws + 33554432);    // dead after kv_a
  unsigned short* attnb = (unsigned short*)(ws + 33554432);    // reuse
  float* qa_part = (float*)(ws + 50331648);                    // dead after rms_q
  unsigned short* kv_bf = (unsigned short*)(ws + 50331648);    // reuse (alive->attn)
  float* ckv_part = (float*)(ws + 100663296);                  // dead after rms_kv
  unsigned short* qa_bf = (unsigned short*)(ws + 138412032);
  unsigned short* ckv_bf = (unsigned short*)(ws + 144703488);
  float* rotf = (float*)(ws + 146800640);
  unsigned short* qfullb = (unsigned short*)(ws + 147324928);  // alive->attn
  unsigned short* Vt = (unsigned short*)(ws + 172490752);      // alive->attn
  unsigned short* Kr = (unsigned short*)(ws + 189267968);      // 256 KiB

  dim3 blk(256);
  auto cvt = [&](const float* src, unsigned short* dst, size_t n) {
    int n8 = (int)(n / 8);
    cvt_kernel<<<(n8 + 255) / 256, blk, 0, stream>>>(src, dst, n8);
  };

  cvt(hs, hs_bf, (size_t)S_LEN * HDIM);
  cvt(q_a_w, wslot, (size_t)RQ_ * HDIM);
  gemm_bf<false, true, false><<<dim3(RQ_ / 128, S_LEN / 128, 4), blk, 0, stream>>>(
      hs_bf, HDIM, wslot, HDIM, qa_part, RQ_, RQ_, HDIM / 4, nullptr);
  cvt(kv_a_w, wslot, (size_t)CKV_W * HDIM);
  gemm_bf<false, true, false><<<dim3((CKV_W + 127) / 128, S_LEN / 128, 8), blk, 0, stream>>>(
      hs_bf, HDIM, wslot, HDIM, ckv_part, CKV_W, CKV_W, HDIM / 8, nullptr);
  rms_sum_q<<<S_LEN, blk, 0, stream>>>(qa_part, q_a_ln, qa_bf);
  rms_sum_kv<<<S_LEN, blk, 0, stream>>>(ckv_part, kv_a_ln, ckv_bf, rotf);
  cvt(q_b_w, wslot, (size_t)QFW * RQ_);
  gemm_bf<true, false, false><<<dim3(QFW / 128, S_LEN / 128), blk, 0, stream>>>(
      qa_bf, RQ_, wslot, RQ_, qfullb, QFW, QFW, RQ_, nullptr);
  cvt(kv_b_w, wslot, (size_t)KVW * 512);
  gemm_bf<true, false, true><<<dim3(KVW / 128, S_LEN / 128), blk, 0, stream>>>(
      ckv_bf, 512, wslot, 512, kv_bf, KVW, KVW, 512, Vt);
  rope_q_kernel<<<(NHEAD * S_LEN * 32 + 255) / 256, blk, 0, stream>>>(qfullb, freqs);
  rope_k_kernel<<<(S_LEN * 32 + 255) / 256, blk, 0, stream>>>(rotf, freqs, Kr);
  attn_kernel<<<dim3(1024), blk, 0, stream>>>(qfullb, kv_bf, Kr, Vt, attnb);
  cvt(o_w, wslot, (size_t)HDIM * HDIM);
  gemm_bf<false, false, false><<<dim3(HDIM / 128, S_LEN / 128), blk, 0, stream>>>(
      attnb, HDIM, wslot, HDIM, out, HDIM, HDIM, HDIM, nullptr);
}

// Round 20
// 519.200 us; speedup vs baseline: 1.4435x; 1.0086x over previous
//
#include <hip/hip_runtime.h>
#define S_LEN 2048
#define HDIM 4096
#define NHEAD 32
#define QKD 192
#define RQ_ 1536
#define CKV_W 576
#define NQKV 2112
#define KVW 8192
#define QFW 6144
#define SC2F 0.1041216313667742f

typedef float f32x4 __attribute__((ext_vector_type(4)));
typedef __bf16 bf16x8 __attribute__((ext_vector_type(8)));

__device__ __forceinline__ unsigned short f2bf(float f) {
  unsigned int u = __float_as_uint(f);
  u += 0x7fffu + ((u >> 16) & 1u);
  return (unsigned short)(u >> 16);
}
__device__ __forceinline__ float b2f(unsigned short u) {
  return __uint_as_float((unsigned int)u << 16);
}
__device__ __forceinline__ float ex2(float x) { return exp2f(x); }

__device__ __forceinline__ void stage16(const void* g, void* lds_base, int lane) {
  __builtin_amdgcn_global_load_lds(
      (const __attribute__((address_space(1))) unsigned int*)g,
      (__attribute__((address_space(3))) unsigned int*)lds_base, 16, 0, 0);
}

__global__ __launch_bounds__(256) void cvt_kernel(
    const float* __restrict__ in, unsigned short* __restrict__ out, int n8) {
  int i = blockIdx.x * 256 + threadIdx.x;
  if (i >= n8) return;
  const float4* p = reinterpret_cast<const float4*>(in) + (size_t)i * 2;
  float4 a = p[0], b = p[1];
  unsigned long long lo = (unsigned long long)f2bf(a.x) | ((unsigned long long)f2bf(a.y) << 16)
      | ((unsigned long long)f2bf(a.z) << 32) | ((unsigned long long)f2bf(a.w) << 48);
  unsigned long long hi = (unsigned long long)f2bf(b.x) | ((unsigned long long)f2bf(b.y) << 16)
      | ((unsigned long long)f2bf(b.z) << 32) | ((unsigned long long)f2bf(b.w) << 48);
  unsigned long long* q = reinterpret_cast<unsigned long long*>(out) + (size_t)i * 2;
  q[0] = lo; q[1] = hi;
}

// BK=32 2-phase dbuf 128x128 GEMM, M-fast XCD decode.
// VSCAT: V-half 128-col tiles scatter transposed into VtOut.
template<bool BF16OUT, bool SPLITK, bool VSCAT>
__global__ __launch_bounds__(256) void gemm_bf(
    const unsigned short* __restrict__ A, int lda,
    const unsigned short* __restrict__ B, int ldb,
    void* __restrict__ Cv, int ldc, int N, int K,
    unsigned short* __restrict__ VtOut) {
  __shared__ unsigned short As[2][4][128][8];
  __shared__ unsigned short Bs[2][4][128][8];
  const int tid = threadIdx.x, lane = tid & 63, w = tid >> 6;
  const int gx = (int)gridDim.x, gy = (int)gridDim.y;
  const int nwg = gx * gy;
  int lin = (int)blockIdx.y * gx + (int)blockIdx.x;
  if ((nwg & 7) == 0) lin = (lin & 7) * (nwg >> 3) + (lin >> 3);
  const int bm = (lin % gy) * 128, bn = (lin / gy) * 128;
  const int koff = SPLITK ? (int)blockIdx.z * K : 0;
  const int wr = (w >> 1) * 64, wc = (w & 1) * 64;
  const int lg = lane >> 4, lm = lane & 15;
  f32x4 acc[4][4] = {};
  const int arow = bm + lane;
  int brow = bn + lane; if (brow >= N) brow = N - 1;

  auto STAGE = [&](int buf, int k0) {
#pragma unroll
    for (int i = 0; i < 2; ++i) {
      stage16(A + (size_t)(arow + i * 64) * lda + koff + k0 + w * 8, &As[buf][w][i * 64][0], lane);
      int br2 = brow + i * 64; if (br2 >= N) br2 = N - 1;
      stage16(B + (size_t)br2 * ldb + koff + k0 + w * 8, &Bs[buf][w][i * 64][0], lane);
    }
  };
  STAGE(0, 0);
  __syncthreads();
  int cur = 0;
  for (int k0 = 0; k0 < K; k0 += 32) {
    if (k0 + 32 < K) STAGE(cur ^ 1, k0 + 32);
    bf16x8 af[4], bf[4];
#pragma unroll
    for (int i = 0; i < 4; ++i)
      af[i] = *reinterpret_cast<const bf16x8*>(&As[cur][lg][wr + i * 16 + lm][0]);
#pragma unroll
    for (int j = 0; j < 4; ++j)
      bf[j] = *reinterpret_cast<const bf16x8*>(&Bs[cur][lg][wc + j * 16 + lm][0]);
    __builtin_amdgcn_s_setprio(1);
#pragma unroll
    for (int i = 0; i < 4; ++i)
#pragma unroll
      for (int j = 0; j < 4; ++j)
        acc[i][j] = __builtin_amdgcn_mfma_f32_16x16x32_bf16(af[i], bf[j], acc[i][j], 0, 0, 0);
    __builtin_amdgcn_s_setprio(0);
    __syncthreads();
    cur ^= 1;
  }

  if constexpr (VSCAT) {
    if (bn & 128) {
      const int h2 = bn >> 8;
#pragma unroll
      for (int i = 0; i < 4; ++i)
#pragma unroll
        for (int j = 0; j < 4; ++j) {
          int d = wc + j * 16 + lm;
          unsigned long long pk =
                (unsigned long long)f2bf(acc[i][j][0])
              | ((unsigned long long)f2bf(acc[i][j][1]) << 16)
              | ((unsigned long long)f2bf(acc[i][j][2]) << 32)
              | ((unsigned long long)f2bf(acc[i][j][3]) << 48);
          *reinterpret_cast<unsigned long long*>(
              VtOut + (size_t)(h2 * 128 + d) * S_LEN + bm + wr + i * 16 + lg * 4) = pk;
        }
      return;
    }
  }

  size_t zoff = SPLITK ? (size_t)blockIdx.z * S_LEN * N : 0;
#pragma unroll
  for (int i = 0; i < 4; ++i)
#pragma unroll
    for (int j = 0; j < 4; ++j)
#pragma unroll
      for (int r = 0; r < 4; ++r) {
        int row = bm + wr + i * 16 + lg * 4 + r;
        int col = bn + wc + j * 16 + lm;
        if (col < N) {
          if constexpr (BF16OUT)
            ((unsigned short*)Cv)[(size_t)row * ldc + col] = f2bf(acc[i][j][r]);
          else
            ((float*)Cv)[zoff + (size_t)row * ldc + col] = acc[i][j][r];
        }
      }
}

// Sum 4 K-slice partials (cols 0..1535 of [S][2112]) + RMSNorm -> bf16
__global__ __launch_bounds__(256) void rms_sum_q(
    const float* __restrict__ P, const float* __restrict__ w,
    unsigned short* __restrict__ y) {
  __shared__ float red[4];
  const int row = blockIdx.x, tid = threadIdx.x;
  const float* base = P + (size_t)row * NQKV;
  float x[6]; float ss = 0.f;
#pragma unroll
  for (int ii = 0; ii < 6; ++ii) {
    int j = tid + ii * 256;
    float v = 0.f;
#pragma unroll
    for (int z = 0; z < 4; ++z) v += base[(size_t)z * S_LEN * NQKV + j];
    x[ii] = v; ss += v * v;
  }
#pragma unroll
  for (int off = 1; off < 64; off <<= 1) ss += __shfl_xor(ss, off, 64);
  if ((tid & 63) == 0) red[tid >> 6] = ss;
  __syncthreads();
  float scale = rsqrtf((red[0] + red[1] + red[2] + red[3]) / (float)RQ_ + 1e-6f);
  unsigned short* q = y + (size_t)row * RQ_;
#pragma unroll
  for (int ii = 0; ii < 6; ++ii) {
    int j = tid + ii * 256;
    q[j] = f2bf(x[ii] * scale * w[j]);
  }
}

// Sum 4 partials (cols 1536..2111) + RMSNorm(512) -> bf16; RoPE rot tail -> Kr
__global__ __launch_bounds__(256) void rms_sum_kv(
    const float* __restrict__ P, const float* __restrict__ w,
    const float* __restrict__ freqs,
    unsigned short* __restrict__ y, unsigned short* __restrict__ Kr) {
  __shared__ float red[4];
  const int row = blockIdx.x, tid = threadIdx.x;
  const float* base = P + (size_t)row * NQKV + RQ_;
  float x0 = 0.f, x1 = 0.f, x2 = 0.f;
#pragma unroll
  for (int z = 0; z < 4; ++z) {
    const float* b = base + (size_t)z * S_LEN * NQKV;
    x0 += b[tid]; x1 += b[tid + 256];
    if (tid < 64) x2 += b[tid + 512];
  }
  float ss = x0 * x0 + x1 * x1;
#pragma unroll
  for (int off = 1; off < 64; off <<= 1) ss += __shfl_xor(ss, off, 64);
  if ((tid & 63) == 0) red[tid >> 6] = ss;
  __syncthreads();
  float scale = rsqrtf((red[0] + red[1] + red[2] + red[3]) / 512.0f + 1e-6f);
  unsigned short* q = y + (size_t)row * 512;
  q[tid] = f2bf(x0 * scale * w[tid]);
  q[tid + 256] = f2bf(x1 * scale * w[tid + 256]);
  if (tid < 64) {
    // RoPE pair exchange: partner lane holds the other half of (2r, 2r+1)
    float part = __shfl_xor(x2, 1, 64);
    int r = tid >> 1;
    float f = freqs[(size_t)row * 32 + r];
    float c = cosf(f), sn = sinf(f);
    float out = (tid & 1) ? (part * sn + x2 * c)    // odd: xr*s + xi*c
                          : (x2 * c - part * sn);   // even: xr*c - xi*s
    Kr[(size_t)row * 64 + tid] = f2bf(out);
  }
}

// In-place RoPE on qfullb cols [h*192+128, h*192+192)
__global__ __launch_bounds__(256) void rope_q_kernel(
    unsigned short* __restrict__ qf, const float* __restrict__ freqs) {
  int idx = blockIdx.x * 256 + threadIdx.x;
  if (idx >= NHEAD * S_LEN * 32) return;
  int r = idx & 31, s = (idx >> 5) & (S_LEN - 1), h = idx >> 16;
  unsigned short* p = qf + (size_t)s * QFW + h * QKD + 128 + 2 * r;
  float xr = b2f(p[0]), xi = b2f(p[1]);
  float f = freqs[(size_t)s * 32 + r];
  float c = cosf(f), sn = sinf(f);
  *reinterpret_cast<unsigned int*>(p) =
      (unsigned int)f2bf(xr * c - xi * sn) | ((unsigned int)f2bf(xr * sn + xi * c) << 16);
}

// QBLK=64 attn; Q from qfullb, K-pass from kv_bf, K-rope from Kr, V from Vt.
__global__ __launch_bounds__(256, 3) void attn_kernel(
    const unsigned short* __restrict__ Qf,
    const unsigned short* __restrict__ KV,
    const unsigned short* __restrict__ Kr,
    const unsigned short* __restrict__ Vt,
    unsigned short* __restrict__ O) {
  __shared__ unsigned short Ks[2][32 * 192];
  __shared__ unsigned short Vs[2][128 * 32];
  __shared__ unsigned short Ps[4][16 * 32];
  const int tid = threadIdx.x, lane = tid & 63, w = tid >> 6;
  const int wg = (int)blockIdx.x;
  const int lin = (wg & 7) * 128 + (wg >> 3);
  const int h = lin >> 5;
  const int qt = 31 - (lin & 31);
  const int qr0 = qt * 64 + w * 16;
  const int lg = lane >> 4, lm = lane & 15, lm7 = lane & 7;
  const unsigned short* Qh = Qf + h * QKD;
  const int hoff = h * 256;
  const unsigned short* Vh = Vt + (size_t)h * 128 * S_LEN;

  bf16x8 qf[6];
#pragma unroll
  for (int f = 0; f < 6; ++f)
    qf[f] = *reinterpret_cast<const bf16x8*>(
        Qh + (size_t)(qr0 + lm) * QFW + f * 32 + lg * 8);

  f32x4 o[8] = {};
  float l[4] = {};

  auto STAGE = [&](int b, int kp) {
#pragma unroll
    for (int i = 0; i < 3; ++i) {
      int fb = (w * 3 + i) * 64 + lane;
      int row = fb / 24;
      int blk = fb - row * 24;
      int gb = (blk & ~7) | ((blk ^ row) & 7);
      const unsigned short* src = (blk < 16)
          ? KV + (size_t)(kp + row) * KVW + hoff + gb * 8
          : Kr + (size_t)(kp + row) * 64 + (gb - 16) * 8;
      stage16(src, &Ks[b][(w * 3 + i) * 512], lane);
    }
#pragma unroll
    for (int i = 0; i < 2; ++i) {
      int fb = (w * 2 + i) * 64 + lane;
      int row = fb >> 2;
      int blk = fb & 3;
      stage16(Vh + (size_t)row * S_LEN + kp + blk * 8, &Vs[b][(w * 2 + i) * 512], lane);
    }
  };

  const int ntiles = (qt + 1) * 2;
  STAGE(0, 0);
  __syncthreads();
  int buf = 0;
  for (int ti = 0; ti < ntiles; ++ti) {
    const int kp = ti * 32;
    if (ti + 1 < ntiles) STAGE(buf ^ 1, kp + 32);
    if (kp <= qr0 + 15) {
      f32x4 sc[2] = {};
      __builtin_amdgcn_s_setprio(1);
#pragma unroll
      for (int f = 0; f < 6; ++f)
#pragma unroll
        for (int c = 0; c < 2; ++c) {
          int blk = f * 4 + lg;
          int sb = (blk & ~7) | ((blk ^ lm7) & 7);
          bf16x8 kf = *reinterpret_cast<const bf16x8*>(&Ks[buf][(c * 16 + lm) * 192 + sb * 8]);
          sc[c] = __builtin_amdgcn_mfma_f32_16x16x32_bf16(qf[f], kf, sc[c], 0, 0, 0);
        }
      __builtin_amdgcn_s_setprio(0);
      const int rb = qr0 + lg * 4;
#pragma unroll
      for (int r = 0; r < 4; ++r) {
        const int row = rb + r;
        float v0 = fmaf(sc[0][r], SC2F, -32.f); if (kp + lm > row) v0 = -1e9f;
        float v1 = fmaf(sc[1][r], SC2F, -32.f); if (kp + 16 + lm > row) v1 = -1e9f;
        float p0 = ex2(v0), p1 = ex2(v1);
        l[r] += p0 + p1;
        int pr = lg * 4 + r;
        int s3 = pr & 3;
        int b0 = lm >> 3;
        unsigned short* pp = &Ps[w][pr * 32];
        pp[((b0 ^ s3) << 3) + lm7] = f2bf(p0);
        pp[(((2 + b0) ^ s3) << 3) + lm7] = f2bf(p1);
      }
      bf16x8 pa = *reinterpret_cast<const bf16x8*>(
          &Ps[w][lm * 32 + ((lg ^ (lm & 3)) << 3)]);
      __builtin_amdgcn_s_setprio(1);
#pragma unroll
      for (int d = 0; d < 8; ++d) {
        bf16x8 vf = *reinterpret_cast<const bf16x8*>(&Vs[buf][(d * 16 + lm) * 32 + lg * 8]);
        o[d] = __builtin_amdgcn_mfma_f32_16x16x32_bf16(pa, vf, o[d], 0, 0, 0);
      }
      __builtin_amdgcn_s_setprio(0);
    }
    __syncthreads();
    buf ^= 1;
  }
#pragma unroll
  for (int r = 0; r < 4; ++r) {
    float t = l[r];
#pragma unroll
    for (int off = 1; off < 16; off <<= 1) t += __shfl_xor(t, off, 16);
    float inv = 1.0f / t;
    int row = qr0 + lg * 4 + r;
#pragma unroll
    for (int d = 0; d < 8; ++d)
      O[(size_t)row * 4096 + h * 128 + d * 16 + lm] = f2bf(o[d][r] * inv);
  }
}

extern "C" void kernel_launch(void* const* d_in, const int* in_sizes, int n_in,
                              void* d_out, int out_size, void* d_ws, size_t ws_size,
                              hipStream_t stream) {
  const float* hs = (const float*)d_in[0];
  const float* freqs = (const float*)d_in[1];
  const float* q_a_w = (const float*)d_in[2];
  const float* q_a_ln = (const float*)d_in[3];
  const float* q_b_w = (const float*)d_in[4];
  const float* kv_a_w = (const float*)d_in[5];
  const float* kv_a_ln = (const float*)d_in[6];
  const float* kv_b_w = (const float*)d_in[7];
  const float* o_w = (const float*)d_in[8];
  float* out = (float*)d_out;

  char* ws = (char*)d_ws;
  unsigned short* wslot = (unsigned short*)(ws + 0);           // 32 MiB
  unsigned short* hs_bf = (unsigned short*)(ws + 33554432);    // dead after qkv_a
  unsigned short* attnb = (unsigned short*)(ws + 33554432);    // reuse
  float* qkv_part = (float*)(ws + 50331648);                   // 69 MiB (4 slices x S x 2112)
  unsigned short* kv_bf = (unsigned short*)(ws + 50331648);    // reuse after rms (alive->attn)
  unsigned short* qa_bf = (unsigned short*)(ws + 138412032);
  unsigned short* ckv_bf = (unsigned short*)(ws + 144703488);
  unsigned short* qfullb = (unsigned short*)(ws + 147324928);  // alive->attn
  unsigned short* Vt = (unsigned short*)(ws + 172490752);      // alive->attn
  unsigned short* Kr = (unsigned short*)(ws + 189267968);      // 256 KiB

  dim3 blk(256);
  auto cvt = [&](const float* src, unsigned short* dst, size_t n) {
    int n8 = (int)(n / 8);
    cvt_kernel<<<(n8 + 255) / 256, blk, 0, stream>>>(src, dst, n8);
  };

  cvt(hs, hs_bf, (size_t)S_LEN * HDIM);
  // combined q_a || kv_a weights -> wslot (rows 0..1535 q, 1536..2111 kv)
  cvt(q_a_w, wslot, (size_t)RQ_ * HDIM);
  cvt(kv_a_w, wslot + (size_t)RQ_ * HDIM, (size_t)CKV_W * HDIM);
  // fused q_a + kv_a projection: N=2112, split-K=4, grid 17x16x4 = 1088 blocks
  gemm_bf<false, true, false><<<dim3(17, S_LEN / 128, 4), blk, 0, stream>>>(
      hs_bf, HDIM, wslot, HDIM, qkv_part, NQKV, NQKV, HDIM / 4, nullptr);
  rms_sum_q<<<S_LEN, blk, 0, stream>>>(qkv_part, q_a_ln, qa_bf);
  rms_sum_kv<<<S_LEN, blk, 0, stream>>>(qkv_part, kv_a_ln, freqs, ckv_bf, Kr);
  cvt(q_b_w, wslot, (size_t)QFW * RQ_);
  gemm_bf<true, false, false><<<dim3(QFW / 128, S_LEN / 128), blk, 0, stream>>>(
      qa_bf, RQ_, wslot, RQ_, qfullb, QFW, QFW, RQ_, nullptr);
  cvt(kv_b_w, wslot, (size_t)KVW * 512);
  gemm_bf<true, false, true><<<dim3(KVW / 128, S_LEN / 128), blk, 0, stream>>>(
      ckv_bf, 512, wslot, 512, kv_bf, KVW, KVW, 512, Vt);
  rope_q_kernel<<<(NHEAD * S_LEN * 32 + 255) / 256, blk, 0, stream>>>(qfullb, freqs);
  attn_kernel<<<dim3(1024), blk, 0, stream>>>(qfullb, kv_bf, Kr, Vt, attnb);
  cvt(o_w, wslot, (size_t)HDIM * HDIM);
  gemm_bf<false, false, false><<<dim3(HDIM / 128, S_LEN / 128), blk, 0, stream>>>(
      attnb, HDIM, wslot, HDIM, out, HDIM, HDIM, HDIM, nullptr);
}

// Round 21
// 515.047 us; speedup vs baseline: 1.4551x; 1.0081x over previous
//
#include <hip/hip_runtime.h>
#define S_LEN 2048
#define HDIM 4096
#define NHEAD 32
#define QKD 192
#define RQ_ 1536
#define CKV_W 576
#define NQKV 2112
#define KVW 8192
#define QFW 6144
#define SC2F 0.1041216313667742f

typedef float f32x4 __attribute__((ext_vector_type(4)));
typedef __bf16 bf16x8 __attribute__((ext_vector_type(8)));

__device__ __forceinline__ unsigned short f2bf(float f) {
  unsigned int u = __float_as_uint(f);
  u += 0x7fffu + ((u >> 16) & 1u);
  return (unsigned short)(u >> 16);
}
__device__ __forceinline__ float b2f(unsigned short u) {
  return __uint_as_float((unsigned int)u << 16);
}
__device__ __forceinline__ float ex2(float x) { return exp2f(x); }

__device__ __forceinline__ void stage16(const void* g, void* lds_base, int lane) {
  __builtin_amdgcn_global_load_lds(
      (const __attribute__((address_space(1))) unsigned int*)g,
      (__attribute__((address_space(3))) unsigned int*)lds_base, 16, 0, 0);
}

__global__ __launch_bounds__(256) void cvt_kernel(
    const float* __restrict__ in, unsigned short* __restrict__ out, int n8) {
  int i = blockIdx.x * 256 + threadIdx.x;
  if (i >= n8) return;
  const float4* p = reinterpret_cast<const float4*>(in) + (size_t)i * 2;
  float4 a = p[0], b = p[1];
  unsigned long long lo = (unsigned long long)f2bf(a.x) | ((unsigned long long)f2bf(a.y) << 16)
      | ((unsigned long long)f2bf(a.z) << 32) | ((unsigned long long)f2bf(a.w) << 48);
  unsigned long long hi = (unsigned long long)f2bf(b.x) | ((unsigned long long)f2bf(b.y) << 16)
      | ((unsigned long long)f2bf(b.z) << 32) | ((unsigned long long)f2bf(b.w) << 48);
  unsigned long long* q = reinterpret_cast<unsigned long long*>(out) + (size_t)i * 2;
  q[0] = lo; q[1] = hi;
}

// BK=32 128x128 GEMM, M-fast XCD decode. T4: triple-buffered LDS, stage t+2,
// counted vmcnt(4) + raw s_barrier (prefetch stays in flight across barriers).
template<bool BF16OUT, bool SPLITK, bool VSCAT>
__global__ __launch_bounds__(256) void gemm_bf(
    const unsigned short* __restrict__ A, int lda,
    const unsigned short* __restrict__ B, int ldb,
    void* __restrict__ Cv, int ldc, int N, int K,
    unsigned short* __restrict__ VtOut) {
  __shared__ unsigned short As[3][4][128][8];
  __shared__ unsigned short Bs[3][4][128][8];
  const int tid = threadIdx.x, lane = tid & 63, w = tid >> 6;
  const int gx = (int)gridDim.x, gy = (int)gridDim.y;
  const int nwg = gx * gy;
  int lin = (int)blockIdx.y * gx + (int)blockIdx.x;
  if ((nwg & 7) == 0) lin = (lin & 7) * (nwg >> 3) + (lin >> 3);
  const int bm = (lin % gy) * 128, bn = (lin / gy) * 128;
  const int koff = SPLITK ? (int)blockIdx.z * K : 0;
  const int wr = (w >> 1) * 64, wc = (w & 1) * 64;
  const int lg = lane >> 4, lm = lane & 15;
  f32x4 acc[4][4] = {};
  const int arow = bm + lane;
  int brow = bn + lane; if (brow >= N) brow = N - 1;

  auto STAGE = [&](int buf, int k0) {
#pragma unroll
    for (int i = 0; i < 2; ++i) {
      stage16(A + (size_t)(arow + i * 64) * lda + koff + k0 + w * 8, &As[buf][w][i * 64][0], lane);
      int br2 = brow + i * 64; if (br2 >= N) br2 = N - 1;
      stage16(B + (size_t)br2 * ldb + koff + k0 + w * 8, &Bs[buf][w][i * 64][0], lane);
    }
  };
  STAGE(0, 0);
  if (K > 32) STAGE(1, 32);
  asm volatile("s_waitcnt vmcnt(4)" ::: "memory");
  __builtin_amdgcn_s_barrier();

  int t = 0;
  for (int k0 = 0; k0 < K; k0 += 32, ++t) {
    const int b = t % 3;
    const bool staged = (k0 + 64 < K);
    if (staged) STAGE((t + 2) % 3, k0 + 64);
    bf16x8 af[4], bf[4];
#pragma unroll
    for (int i = 0; i < 4; ++i)
      af[i] = *reinterpret_cast<const bf16x8*>(&As[b][lg][wr + i * 16 + lm][0]);
#pragma unroll
    for (int j = 0; j < 4; ++j)
      bf[j] = *reinterpret_cast<const bf16x8*>(&Bs[b][lg][wc + j * 16 + lm][0]);
    __builtin_amdgcn_s_setprio(1);
#pragma unroll
    for (int i = 0; i < 4; ++i)
#pragma unroll
      for (int j = 0; j < 4; ++j)
        acc[i][j] = __builtin_amdgcn_mfma_f32_16x16x32_bf16(af[i], bf[j], acc[i][j], 0, 0, 0);
    __builtin_amdgcn_s_setprio(0);
    if (staged) asm volatile("s_waitcnt vmcnt(4)" ::: "memory");
    else        asm volatile("s_waitcnt vmcnt(0)" ::: "memory");
    __builtin_amdgcn_s_barrier();
  }

  if constexpr (VSCAT) {
    if (bn & 128) {
      const int h2 = bn >> 8;
#pragma unroll
      for (int i = 0; i < 4; ++i)
#pragma unroll
        for (int j = 0; j < 4; ++j) {
          int d = wc + j * 16 + lm;
          unsigned long long pk =
                (unsigned long long)f2bf(acc[i][j][0])
              | ((unsigned long long)f2bf(acc[i][j][1]) << 16)
              | ((unsigned long long)f2bf(acc[i][j][2]) << 32)
              | ((unsigned long long)f2bf(acc[i][j][3]) << 48);
          *reinterpret_cast<unsigned long long*>(
              VtOut + (size_t)(h2 * 128 + d) * S_LEN + bm + wr + i * 16 + lg * 4) = pk;
        }
      return;
    }
  }

  size_t zoff = SPLITK ? (size_t)blockIdx.z * S_LEN * N : 0;
#pragma unroll
  for (int i = 0; i < 4; ++i)
#pragma unroll
    for (int j = 0; j < 4; ++j)
#pragma unroll
      for (int r = 0; r < 4; ++r) {
        int row = bm + wr + i * 16 + lg * 4 + r;
        int col = bn + wc + j * 16 + lm;
        if (col < N) {
          if constexpr (BF16OUT)
            ((unsigned short*)Cv)[(size_t)row * ldc + col] = f2bf(acc[i][j][r]);
          else
            ((float*)Cv)[zoff + (size_t)row * ldc + col] = acc[i][j][r];
        }
      }
}

__global__ __launch_bounds__(256) void rms_sum_q(
    const float* __restrict__ P, const float* __restrict__ w,
    unsigned short* __restrict__ y) {
  __shared__ float red[4];
  const int row = blockIdx.x, tid = threadIdx.x;
  const float* base = P + (size_t)row * NQKV;
  float x[6]; float ss = 0.f;
#pragma unroll
  for (int ii = 0; ii < 6; ++ii) {
    int j = tid + ii * 256;
    float v = 0.f;
#pragma unroll
    for (int z = 0; z < 4; ++z) v += base[(size_t)z * S_LEN * NQKV + j];
    x[ii] = v; ss += v * v;
  }
#pragma unroll
  for (int off = 1; off < 64; off <<= 1) ss += __shfl_xor(ss, off, 64);
  if ((tid & 63) == 0) red[tid >> 6] = ss;
  __syncthreads();
  float scale = rsqrtf((red[0] + red[1] + red[2] + red[3]) / (float)RQ_ + 1e-6f);
  unsigned short* q = y + (size_t)row * RQ_;
#pragma unroll
  for (int ii = 0; ii < 6; ++ii) {
    int j = tid + ii * 256;
    q[j] = f2bf(x[ii] * scale * w[j]);
  }
}

__global__ __launch_bounds__(256) void rms_sum_kv(
    const float* __restrict__ P, const float* __restrict__ w,
    const float* __restrict__ freqs,
    unsigned short* __restrict__ y, unsigned short* __restrict__ Kr) {
  __shared__ float red[4];
  const int row = blockIdx.x, tid = threadIdx.x;
  const float* base = P + (size_t)row * NQKV + RQ_;
  float x0 = 0.f, x1 = 0.f, x2 = 0.f;
#pragma unroll
  for (int z = 0; z < 4; ++z) {
    const float* b = base + (size_t)z * S_LEN * NQKV;
    x0 += b[tid]; x1 += b[tid + 256];
    if (tid < 64) x2 += b[tid + 512];
  }
  float ss = x0 * x0 + x1 * x1;
#pragma unroll
  for (int off = 1; off < 64; off <<= 1) ss += __shfl_xor(ss, off, 64);
  if ((tid & 63) == 0) red[tid >> 6] = ss;
  __syncthreads();
  float scale = rsqrtf((red[0] + red[1] + red[2] + red[3]) / 512.0f + 1e-6f);
  unsigned short* q = y + (size_t)row * 512;
  q[tid] = f2bf(x0 * scale * w[tid]);
  q[tid + 256] = f2bf(x1 * scale * w[tid + 256]);
  if (tid < 64) {
    float part = __shfl_xor(x2, 1, 64);
    int r = tid >> 1;
    float f = freqs[(size_t)row * 32 + r];
    float c = cosf(f), sn = sinf(f);
    float out = (tid & 1) ? (part * sn + x2 * c)
                          : (x2 * c - part * sn);
    Kr[(size_t)row * 64 + tid] = f2bf(out);
  }
}

__global__ __launch_bounds__(256) void rope_q_kernel(
    unsigned short* __restrict__ qf, const float* __restrict__ freqs) {
  int idx = blockIdx.x * 256 + threadIdx.x;
  if (idx >= NHEAD * S_LEN * 32) return;
  int r = idx & 31, s = (idx >> 5) & (S_LEN - 1), h = idx >> 16;
  unsigned short* p = qf + (size_t)s * QFW + h * QKD + 128 + 2 * r;
  float xr = b2f(p[0]), xi = b2f(p[1]);
  float f = freqs[(size_t)s * 32 + r];
  float c = cosf(f), sn = sinf(f);
  *reinterpret_cast<unsigned int*>(p) =
      (unsigned int)f2bf(xr * c - xi * sn) | ((unsigned int)f2bf(xr * sn + xi * c) << 16);
}

__global__ __launch_bounds__(256, 3) void attn_kernel(
    const unsigned short* __restrict__ Qf,
    const unsigned short* __restrict__ KV,
    const unsigned short* __restrict__ Kr,
    const unsigned short* __restrict__ Vt,
    unsigned short* __restrict__ O) {
  __shared__ unsigned short Ks[2][32 * 192];
  __shared__ unsigned short Vs[2][128 * 32];
  __shared__ unsigned short Ps[4][16 * 32];
  const int tid = threadIdx.x, lane = tid & 63, w = tid >> 6;
  const int wg = (int)blockIdx.x;
  const int lin = (wg & 7) * 128 + (wg >> 3);
  const int h = lin >> 5;
  const int qt = 31 - (lin & 31);
  const int qr0 = qt * 64 + w * 16;
  const int lg = lane >> 4, lm = lane & 15, lm7 = lane & 7;
  const unsigned short* Qh = Qf + h * QKD;
  const int hoff = h * 256;
  const unsigned short* Vh = Vt + (size_t)h * 128 * S_LEN;

  bf16x8 qf[6];
#pragma unroll
  for (int f = 0; f < 6; ++f)
    qf[f] = *reinterpret_cast<const bf16x8*>(
        Qh + (size_t)(qr0 + lm) * QFW + f * 32 + lg * 8);

  f32x4 o[8] = {};
  float l[4] = {};

  auto STAGE = [&](int b, int kp) {
#pragma unroll
    for (int i = 0; i < 3; ++i) {
      int fb = (w * 3 + i) * 64 + lane;
      int row = fb / 24;
      int blk = fb - row * 24;
      int gb = (blk & ~7) | ((blk ^ row) & 7);
      const unsigned short* src = (blk < 16)
          ? KV + (size_t)(kp + row) * KVW + hoff + gb * 8
          : Kr + (size_t)(kp + row) * 64 + (gb - 16) * 8;
      stage16(src, &Ks[b][(w * 3 + i) * 512], lane);
    }
#pragma unroll
    for (int i = 0; i < 2; ++i) {
      int fb = (w * 2 + i) * 64 + lane;
      int row = fb >> 2;
      int blk = fb & 3;
      stage16(Vh + (size_t)row * S_LEN + kp + blk * 8, &Vs[b][(w * 2 + i) * 512], lane);
    }
  };

  const int ntiles = (qt + 1) * 2;
  STAGE(0, 0);
  __syncthreads();
  int buf = 0;
  for (int ti = 0; ti < ntiles; ++ti) {
    const int kp = ti * 32;
    if (ti + 1 < ntiles) STAGE(buf ^ 1, kp + 32);
    if (kp <= qr0 + 15) {
      f32x4 sc[2] = {};
      __builtin_amdgcn_s_setprio(1);
#pragma unroll
      for (int f = 0; f < 6; ++f)
#pragma unroll
        for (int c = 0; c < 2; ++c) {
          int blk = f * 4 + lg;
          int sb = (blk & ~7) | ((blk ^ lm7) & 7);
          bf16x8 kf = *reinterpret_cast<const bf16x8*>(&Ks[buf][(c * 16 + lm) * 192 + sb * 8]);
          sc[c] = __builtin_amdgcn_mfma_f32_16x16x32_bf16(qf[f], kf, sc[c], 0, 0, 0);
        }
      __builtin_amdgcn_s_setprio(0);
      const int rb = qr0 + lg * 4;
#pragma unroll
      for (int r = 0; r < 4; ++r) {
        const int row = rb + r;
        float v0 = fmaf(sc[0][r], SC2F, -32.f); if (kp + lm > row) v0 = -1e9f;
        float v1 = fmaf(sc[1][r], SC2F, -32.f); if (kp + 16 + lm > row) v1 = -1e9f;
        float p0 = ex2(v0), p1 = ex2(v1);
        l[r] += p0 + p1;
        int pr = lg * 4 + r;
        int s3 = pr & 3;
        int b0 = lm >> 3;
        unsigned short* pp = &Ps[w][pr * 32];
        pp[((b0 ^ s3) << 3) + lm7] = f2bf(p0);
        pp[(((2 + b0) ^ s3) << 3) + lm7] = f2bf(p1);
      }
      bf16x8 pa = *reinterpret_cast<const bf16x8*>(
          &Ps[w][lm * 32 + ((lg ^ (lm & 3)) << 3)]);
      __builtin_amdgcn_s_setprio(1);
#pragma unroll
      for (int d = 0; d < 8; ++d) {
        bf16x8 vf = *reinterpret_cast<const bf16x8*>(&Vs[buf][(d * 16 + lm) * 32 + lg * 8]);
        o[d] = __builtin_amdgcn_mfma_f32_16x16x32_bf16(pa, vf, o[d], 0, 0, 0);
      }
      __builtin_amdgcn_s_setprio(0);
    }
    __syncthreads();
    buf ^= 1;
  }
#pragma unroll
  for (int r = 0; r < 4; ++r) {
    float t = l[r];
#pragma unroll
    for (int off = 1; off < 16; off <<= 1) t += __shfl_xor(t, off, 16);
    float inv = 1.0f / t;
    int row = qr0 + lg * 4 + r;
#pragma unroll
    for (int d = 0; d < 8; ++d)
      O[(size_t)row * 4096 + h * 128 + d * 16 + lm] = f2bf(o[d][r] * inv);
  }
}

extern "C" void kernel_launch(void* const* d_in, const int* in_sizes, int n_in,
                              void* d_out, int out_size, void* d_ws, size_t ws_size,
                              hipStream_t stream) {
  const float* hs = (const float*)d_in[0];
  const float* freqs = (const float*)d_in[1];
  const float* q_a_w = (const float*)d_in[2];
  const float* q_a_ln = (const float*)d_in[3];
  const float* q_b_w = (const float*)d_in[4];
  const float* kv_a_w = (const float*)d_in[5];
  const float* kv_a_ln = (const float*)d_in[6];
  const float* kv_b_w = (const float*)d_in[7];
  const float* o_w = (const float*)d_in[8];
  float* out = (float*)d_out;

  char* ws = (char*)d_ws;
  unsigned short* wslot = (unsigned short*)(ws + 0);
  unsigned short* hs_bf = (unsigned short*)(ws + 33554432);
  unsigned short* attnb = (unsigned short*)(ws + 33554432);
  float* qkv_part = (float*)(ws + 50331648);
  unsigned short* kv_bf = (unsigned short*)(ws + 50331648);
  unsigned short* qa_bf = (unsigned short*)(ws + 138412032);
  unsigned short* ckv_bf = (unsigned short*)(ws + 144703488);
  unsigned short* qfullb = (unsigned short*)(ws + 147324928);
  unsigned short* Vt = (unsigned short*)(ws + 172490752);
  unsigned short* Kr = (unsigned short*)(ws + 189267968);

  dim3 blk(256);
  auto cvt = [&](const float* src, unsigned short* dst, size_t n) {
    int n8 = (int)(n / 8);
    cvt_kernel<<<(n8 + 255) / 256, blk, 0, stream>>>(src, dst, n8);
  };

  cvt(hs, hs_bf, (size_t)S_LEN * HDIM);
  cvt(q_a_w, wslot, (size_t)RQ_ * HDIM);
  cvt(kv_a_w, wslot + (size_t)RQ_ * HDIM, (size_t)CKV_W * HDIM);
  gemm_bf<false, true, false><<<dim3(17, S_LEN / 128, 4), blk, 0, stream>>>(
      hs_bf, HDIM, wslot, HDIM, qkv_part, NQKV, NQKV, HDIM / 4, nullptr);
  rms_sum_q<<<S_LEN, blk, 0, stream>>>(qkv_part, q_a_ln, qa_bf);
  rms_sum_kv<<<S_LEN, blk, 0, stream>>>(qkv_part, kv_a_ln, freqs, ckv_bf, Kr);
  cvt(q_b_w, wslot, (size_t)QFW * RQ_);
  gemm_bf<true, false, false><<<dim3(QFW / 128, S_LEN / 128), blk, 0, stream>>>(
      qa_bf, RQ_, wslot, RQ_, qfullb, QFW, QFW, RQ_, nullptr);
  cvt(kv_b_w, wslot, (size_t)KVW * 512);
  gemm_bf<true, false, true><<<dim3(KVW / 128, S_LEN / 128), blk, 0, stream>>>(
      ckv_bf, 512, wslot, 512, kv_bf, KVW, KVW, 512, Vt);
  rope_q_kernel<<<(NHEAD * S_LEN * 32 + 255) / 256, blk, 0, stream>>>(qfullb, freqs);
  attn_kernel<<<dim3(1024), blk, 0, stream>>>(qfullb, kv_bf, Kr, Vt, attnb);
  cvt(o_w, wslot, (size_t)HDIM * HDIM);
  gemm_bf<false, false, false><<<dim3(HDIM / 128, S_LEN / 128), blk, 0, stream>>>(
      attnb, HDIM, wslot, HDIM, out, HDIM, HDIM, HDIM, nullptr);
}

// Round 22
// 510.345 us; speedup vs baseline: 1.4685x; 1.0092x over previous
//
#include <hip/hip_runtime.h>
#define S_LEN 2048
#define HDIM 4096
#define NHEAD 32
#define QKD 192
#define RQ_ 1536
#define CKV_W 576
#define NQKV 2112
#define KVW 8192
#define QFW 6144
#define SC2F 0.1041216313667742f

typedef float f32x4 __attribute__((ext_vector_type(4)));
typedef __bf16 bf16x8 __attribute__((ext_vector_type(8)));

__device__ __forceinline__ unsigned short f2bf(float f) {
  unsigned int u = __float_as_uint(f);
  u += 0x7fffu + ((u >> 16) & 1u);
  return (unsigned short)(u >> 16);
}
__device__ __forceinline__ float b2f(unsigned short u) {
  return __uint_as_float((unsigned int)u << 16);
}
__device__ __forceinline__ float ex2(float x) { return exp2f(x); }

__device__ __forceinline__ void stage16(const void* g, void* lds_base, int lane) {
  __builtin_amdgcn_global_load_lds(
      (const __attribute__((address_space(1))) unsigned int*)g,
      (__attribute__((address_space(3))) unsigned int*)lds_base, 16, 0, 0);
}

__global__ __launch_bounds__(256) void cvt_kernel(
    const float* __restrict__ in, unsigned short* __restrict__ out, int n8) {
  int i = blockIdx.x * 256 + threadIdx.x;
  if (i >= n8) return;
  const float4* p = reinterpret_cast<const float4*>(in) + (size_t)i * 2;
  float4 a = p[0], b = p[1];
  unsigned long long lo = (unsigned long long)f2bf(a.x) | ((unsigned long long)f2bf(a.y) << 16)
      | ((unsigned long long)f2bf(a.z) << 32) | ((unsigned long long)f2bf(a.w) << 48);
  unsigned long long hi = (unsigned long long)f2bf(b.x) | ((unsigned long long)f2bf(b.y) << 16)
      | ((unsigned long long)f2bf(b.z) << 32) | ((unsigned long long)f2bf(b.w) << 48);
  unsigned long long* q = reinterpret_cast<unsigned long long*>(out) + (size_t)i * 2;
  q[0] = lo; q[1] = hi;
}

// BK=32 2-phase dbuf 128x128 GEMM, M-fast XCD decode (R20-proven).
template<bool BF16OUT, bool SPLITK>
__global__ __launch_bounds__(256) void gemm_bf(
    const unsigned short* __restrict__ A, int lda,
    const unsigned short* __restrict__ B, int ldb,
    void* __restrict__ Cv, int ldc, int N, int K) {
  __shared__ unsigned short As[2][4][128][8];
  __shared__ unsigned short Bs[2][4][128][8];
  const int tid = threadIdx.x, lane = tid & 63, w = tid >> 6;
  const int gx = (int)gridDim.x, gy = (int)gridDim.y;
  const int nwg = gx * gy;
  int lin = (int)blockIdx.y * gx + (int)blockIdx.x;
  if ((nwg & 7) == 0) lin = (lin & 7) * (nwg >> 3) + (lin >> 3);
  const int bm = (lin % gy) * 128, bn = (lin / gy) * 128;
  const int koff = SPLITK ? (int)blockIdx.z * K : 0;
  const int wr = (w >> 1) * 64, wc = (w & 1) * 64;
  const int lg = lane >> 4, lm = lane & 15;
  f32x4 acc[4][4] = {};
  const int arow = bm + lane;
  int brow = bn + lane; if (brow >= N) brow = N - 1;

  auto STAGE = [&](int buf, int k0) {
#pragma unroll
    for (int i = 0; i < 2; ++i) {
      stage16(A + (size_t)(arow + i * 64) * lda + koff + k0 + w * 8, &As[buf][w][i * 64][0], lane);
      int br2 = brow + i * 64; if (br2 >= N) br2 = N - 1;
      stage16(B + (size_t)br2 * ldb + koff + k0 + w * 8, &Bs[buf][w][i * 64][0], lane);
    }
  };
  STAGE(0, 0);
  __syncthreads();
  int cur = 0;
  for (int k0 = 0; k0 < K; k0 += 32) {
    if (k0 + 32 < K) STAGE(cur ^ 1, k0 + 32);
    bf16x8 af[4], bf[4];
#pragma unroll
    for (int i = 0; i < 4; ++i)
      af[i] = *reinterpret_cast<const bf16x8*>(&As[cur][lg][wr + i * 16 + lm][0]);
#pragma unroll
    for (int j = 0; j < 4; ++j)
      bf[j] = *reinterpret_cast<const bf16x8*>(&Bs[cur][lg][wc + j * 16 + lm][0]);
    __builtin_amdgcn_s_setprio(1);
#pragma unroll
    for (int i = 0; i < 4; ++i)
#pragma unroll
      for (int j = 0; j < 4; ++j)
        acc[i][j] = __builtin_amdgcn_mfma_f32_16x16x32_bf16(af[i], bf[j], acc[i][j], 0, 0, 0);
    __builtin_amdgcn_s_setprio(0);
    __syncthreads();
    cur ^= 1;
  }
  size_t zoff = SPLITK ? (size_t)blockIdx.z * S_LEN * N : 0;
#pragma unroll
  for (int i = 0; i < 4; ++i)
#pragma unroll
    for (int j = 0; j < 4; ++j)
#pragma unroll
      for (int r = 0; r < 4; ++r) {
        int row = bm + wr + i * 16 + lg * 4 + r;
        int col = bn + wc + j * 16 + lm;
        if (col < N) {
          if constexpr (BF16OUT)
            ((unsigned short*)Cv)[(size_t)row * ldc + col] = f2bf(acc[i][j][r]);
          else
            ((float*)Cv)[zoff + (size_t)row * ldc + col] = acc[i][j][r];
        }
      }
}

// q_b and kv_b in ONE dispatch (tail overlap). Blocks [0,nwg1) -> GEMM1
// (q_b, bf16 C). Blocks [nwg1,..) -> GEMM2 (kv_b, bf16 C + Vt scatter).
__global__ __launch_bounds__(256) void gemm_dual(
    const unsigned short* __restrict__ A1, int lda1,
    const unsigned short* __restrict__ B1, int ldb1,
    unsigned short* __restrict__ C1, int ldc1, int K1, int nwg1,
    const unsigned short* __restrict__ A2, int lda2,
    const unsigned short* __restrict__ B2, int ldb2,
    unsigned short* __restrict__ C2, int ldc2, int K2,
    unsigned short* __restrict__ VtOut) {
  __shared__ unsigned short As[2][4][128][8];
  __shared__ unsigned short Bs[2][4][128][8];
  const int tid = threadIdx.x, lane = tid & 63, w = tid >> 6;
  const int raw = (int)blockIdx.x;
  const bool second = (raw >= nwg1);
  const int nwg = second ? ((int)gridDim.x - nwg1) : nwg1;
  int lin = second ? raw - nwg1 : raw;
  lin = (lin & 7) * (nwg >> 3) + (lin >> 3);     // both sub-grids %8==0
  const int gy = S_LEN / 128;
  const int bm = (lin % gy) * 128, bn = (lin / gy) * 128;
  const unsigned short* A = second ? A2 : A1;
  const unsigned short* B = second ? B2 : B1;
  unsigned short* C = second ? C2 : C1;
  const int lda = second ? lda2 : lda1;
  const int ldb = second ? ldb2 : ldb1;
  const int ldc = second ? ldc2 : ldc1;
  const int K = second ? K2 : K1;
  const int wr = (w >> 1) * 64, wc = (w & 1) * 64;
  const int lg = lane >> 4, lm = lane & 15;
  f32x4 acc[4][4] = {};
  const int arow = bm + lane;
  const int brow = bn + lane;

  auto STAGE = [&](int buf, int k0) {
#pragma unroll
    for (int i = 0; i < 2; ++i) {
      stage16(A + (size_t)(arow + i * 64) * lda + k0 + w * 8, &As[buf][w][i * 64][0], lane);
      stage16(B + (size_t)(brow + i * 64) * ldb + k0 + w * 8, &Bs[buf][w][i * 64][0], lane);
    }
  };
  STAGE(0, 0);
  __syncthreads();
  int cur = 0;
  for (int k0 = 0; k0 < K; k0 += 32) {
    if (k0 + 32 < K) STAGE(cur ^ 1, k0 + 32);
    bf16x8 af[4], bf[4];
#pragma unroll
    for (int i = 0; i < 4; ++i)
      af[i] = *reinterpret_cast<const bf16x8*>(&As[cur][lg][wr + i * 16 + lm][0]);
#pragma unroll
    for (int j = 0; j < 4; ++j)
      bf[j] = *reinterpret_cast<const bf16x8*>(&Bs[cur][lg][wc + j * 16 + lm][0]);
    __builtin_amdgcn_s_setprio(1);
#pragma unroll
    for (int i = 0; i < 4; ++i)
#pragma unroll
      for (int j = 0; j < 4; ++j)
        acc[i][j] = __builtin_amdgcn_mfma_f32_16x16x32_bf16(af[i], bf[j], acc[i][j], 0, 0, 0);
    __builtin_amdgcn_s_setprio(0);
    __syncthreads();
    cur ^= 1;
  }

  if (second && (bn & 128)) {   // kv_b V-half: scatter transposed into Vt
    const int h2 = bn >> 8;
#pragma unroll
    for (int i = 0; i < 4; ++i)
#pragma unroll
      for (int j = 0; j < 4; ++j) {
        int d = wc + j * 16 + lm;
        unsigned long long pk =
              (unsigned long long)f2bf(acc[i][j][0])
            | ((unsigned long long)f2bf(acc[i][j][1]) << 16)
            | ((unsigned long long)f2bf(acc[i][j][2]) << 32)
            | ((unsigned long long)f2bf(acc[i][j][3]) << 48);
        *reinterpret_cast<unsigned long long*>(
            VtOut + (size_t)(h2 * 128 + d) * S_LEN + bm + wr + i * 16 + lg * 4) = pk;
      }
    return;
  }
#pragma unroll
  for (int i = 0; i < 4; ++i)
#pragma unroll
    for (int j = 0; j < 4; ++j)
#pragma unroll
      for (int r = 0; r < 4; ++r) {
        int row = bm + wr + i * 16 + lg * 4 + r;
        int col = bn + wc + j * 16 + lm;
        C[(size_t)row * ldc + col] = f2bf(acc[i][j][r]);
      }
}

// Fused: sum 4 K-slice partials over full row (2112), RMSNorm q (1536) +
// RMSNorm kv (512) + RoPE rot tail -> Kr. One block per row.
__global__ __launch_bounds__(256) void rms_fused(
    const float* __restrict__ P, const float* __restrict__ wq,
    const float* __restrict__ wkv, const float* __restrict__ freqs,
    unsigned short* __restrict__ yq, unsigned short* __restrict__ ykv,
    unsigned short* __restrict__ Kr) {
  __shared__ float red[8];
  const int row = blockIdx.x, tid = threadIdx.x;
  const float* base = P + (size_t)row * NQKV;
  float xq[6]; float ssq = 0.f;
#pragma unroll
  for (int ii = 0; ii < 6; ++ii) {
    int j = tid + ii * 256;
    float v = 0.f;
#pragma unroll
    for (int z = 0; z < 4; ++z) v += base[(size_t)z * S_LEN * NQKV + j];
    xq[ii] = v; ssq += v * v;
  }
  const float* bkv = base + RQ_;
  float x0 = 0.f, x1 = 0.f, x2 = 0.f;
#pragma unroll
  for (int z = 0; z < 4; ++z) {
    const float* b = bkv + (size_t)z * S_LEN * NQKV;
    x0 += b[tid]; x1 += b[tid + 256];
    if (tid < 64) x2 += b[tid + 512];
  }
  float sskv = x0 * x0 + x1 * x1;
#pragma unroll
  for (int off = 1; off < 64; off <<= 1) {
    ssq += __shfl_xor(ssq, off, 64);
    sskv += __shfl_xor(sskv, off, 64);
  }
  if ((tid & 63) == 0) { red[tid >> 6] = ssq; red[4 + (tid >> 6)] = sskv; }
  __syncthreads();
  float sq = rsqrtf((red[0] + red[1] + red[2] + red[3]) / (float)RQ_ + 1e-6f);
  float skv = rsqrtf((red[4] + red[5] + red[6] + red[7]) / 512.0f + 1e-6f);
  unsigned short* q = yq + (size_t)row * RQ_;
#pragma unroll
  for (int ii = 0; ii < 6; ++ii) {
    int j = tid + ii * 256;
    q[j] = f2bf(xq[ii] * sq * wq[j]);
  }
  unsigned short* k = ykv + (size_t)row * 512;
  k[tid] = f2bf(x0 * skv * wkv[tid]);
  k[tid + 256] = f2bf(x1 * skv * wkv[tid + 256]);
  if (tid < 64) {
    float part = __shfl_xor(x2, 1, 64);
    int r = tid >> 1;
    float f = freqs[(size_t)row * 32 + r];
    float c = cosf(f), sn = sinf(f);
    float out = (tid & 1) ? (part * sn + x2 * c) : (x2 * c - part * sn);
    Kr[(size_t)row * 64 + tid] = f2bf(out);
  }
}

__global__ __launch_bounds__(256) void rope_q_kernel(
    unsigned short* __restrict__ qf, const float* __restrict__ freqs) {
  int idx = blockIdx.x * 256 + threadIdx.x;
  if (idx >= NHEAD * S_LEN * 32) return;
  int r = idx & 31, s = (idx >> 5) & (S_LEN - 1), h = idx >> 16;
  unsigned short* p = qf + (size_t)s * QFW + h * QKD + 128 + 2 * r;
  float xr = b2f(p[0]), xi = b2f(p[1]);
  float f = freqs[(size_t)s * 32 + r];
  float c = cosf(f), sn = sinf(f);
  *reinterpret_cast<unsigned int*>(p) =
      (unsigned int)f2bf(xr * c - xi * sn) | ((unsigned int)f2bf(xr * sn + xi * c) << 16);
}

__global__ __launch_bounds__(256, 3) void attn_kernel(
    const unsigned short* __restrict__ Qf,
    const unsigned short* __restrict__ KV,
    const unsigned short* __restrict__ Kr,
    const unsigned short* __restrict__ Vt,
    unsigned short* __restrict__ O) {
  __shared__ unsigned short Ks[2][32 * 192];
  __shared__ unsigned short Vs[2][128 * 32];
  __shared__ unsigned short Ps[4][16 * 32];
  const int tid = threadIdx.x, lane = tid & 63, w = tid >> 6;
  const int wg = (int)blockIdx.x;
  const int lin = (wg & 7) * 128 + (wg >> 3);
  const int h = lin >> 5;
  const int qt = 31 - (lin & 31);
  const int qr0 = qt * 64 + w * 16;
  const int lg = lane >> 4, lm = lane & 15, lm7 = lane & 7;
  const unsigned short* Qh = Qf + h * QKD;
  const int hoff = h * 256;
  const unsigned short* Vh = Vt + (size_t)h * 128 * S_LEN;

  bf16x8 qf[6];
#pragma unroll
  for (int f = 0; f < 6; ++f)
    qf[f] = *reinterpret_cast<const bf16x8*>(
        Qh + (size_t)(qr0 + lm) * QFW + f * 32 + lg * 8);

  f32x4 o[8] = {};
  float l[4] = {};

  auto STAGE = [&](int b, int kp) {
#pragma unroll
    for (int i = 0; i < 3; ++i) {
      int fb = (w * 3 + i) * 64 + lane;
      int row = fb / 24;
      int blk = fb - row * 24;
      int gb = (blk & ~7) | ((blk ^ row) & 7);
      const unsigned short* src = (blk < 16)
          ? KV + (size_t)(kp + row) * KVW + hoff + gb * 8
          : Kr + (size_t)(kp + row) * 64 + (gb - 16) * 8;
      stage16(src, &Ks[b][(w * 3 + i) * 512], lane);
    }
#pragma unroll
    for (int i = 0; i < 2; ++i) {
      int fb = (w * 2 + i) * 64 + lane;
      int row = fb >> 2;
      int blk = fb & 3;
      stage16(Vh + (size_t)row * S_LEN + kp + blk * 8, &Vs[b][(w * 2 + i) * 512], lane);
    }
  };

  const int ntiles = (qt + 1) * 2;
  STAGE(0, 0);
  __syncthreads();
  int buf = 0;
  for (int ti = 0; ti < ntiles; ++ti) {
    const int kp = ti * 32;
    if (ti + 1 < ntiles) STAGE(buf ^ 1, kp + 32);
    if (kp <= qr0 + 15) {
      f32x4 sc[2] = {};
      __builtin_amdgcn_s_setprio(1);
#pragma unroll
      for (int f = 0; f < 6; ++f)
#pragma unroll
        for (int c = 0; c < 2; ++c) {
          int blk = f * 4 + lg;
          int sb = (blk & ~7) | ((blk ^ lm7) & 7);
          bf16x8 kf = *reinterpret_cast<const bf16x8*>(&Ks[buf][(c * 16 + lm) * 192 + sb * 8]);
          sc[c] = __builtin_amdgcn_mfma_f32_16x16x32_bf16(qf[f], kf, sc[c], 0, 0, 0);
        }
      __builtin_amdgcn_s_setprio(0);
      const int rb = qr0 + lg * 4;
#pragma unroll
      for (int r = 0; r < 4; ++r) {
        const int row = rb + r;
        float v0 = fmaf(sc[0][r], SC2F, -32.f); if (kp + lm > row) v0 = -1e9f;
        float v1 = fmaf(sc[1][r], SC2F, -32.f); if (kp + 16 + lm > row) v1 = -1e9f;
        float p0 = ex2(v0), p1 = ex2(v1);
        l[r] += p0 + p1;
        int pr = lg * 4 + r;
        int s3 = pr & 3;
        int b0 = lm >> 3;
        unsigned short* pp = &Ps[w][pr * 32];
        pp[((b0 ^ s3) << 3) + lm7] = f2bf(p0);
        pp[(((2 + b0) ^ s3) << 3) + lm7] = f2bf(p1);
      }
      bf16x8 pa = *reinterpret_cast<const bf16x8*>(
          &Ps[w][lm * 32 + ((lg ^ (lm & 3)) << 3)]);
      __builtin_amdgcn_s_setprio(1);
#pragma unroll
      for (int d = 0; d < 8; ++d) {
        bf16x8 vf = *reinterpret_cast<const bf16x8*>(&Vs[buf][(d * 16 + lm) * 32 + lg * 8]);
        o[d] = __builtin_amdgcn_mfma_f32_16x16x32_bf16(pa, vf, o[d], 0, 0, 0);
      }
      __builtin_amdgcn_s_setprio(0);
    }
    __syncthreads();
    buf ^= 1;
  }
#pragma unroll
  for (int r = 0; r < 4; ++r) {
    float t = l[r];
#pragma unroll
    for (int off = 1; off < 16; off <<= 1) t += __shfl_xor(t, off, 16);
    float inv = 1.0f / t;
    int row = qr0 + lg * 4 + r;
#pragma unroll
    for (int d = 0; d < 8; ++d)
      O[(size_t)row * 4096 + h * 128 + d * 16 + lm] = f2bf(o[d][r] * inv);
  }
}

extern "C" void kernel_launch(void* const* d_in, const int* in_sizes, int n_in,
                              void* d_out, int out_size, void* d_ws, size_t ws_size,
                              hipStream_t stream) {
  const float* hs = (const float*)d_in[0];
  const float* freqs = (const float*)d_in[1];
  const float* q_a_w = (const float*)d_in[2];
  const float* q_a_ln = (const float*)d_in[3];
  const float* q_b_w = (const float*)d_in[4];
  const float* kv_a_w = (const float*)d_in[5];
  const float* kv_a_ln = (const float*)d_in[6];
  const float* kv_b_w = (const float*)d_in[7];
  const float* o_w = (const float*)d_in[8];
  float* out = (float*)d_out;

  char* ws = (char*)d_ws;
  unsigned short* wslot = (unsigned short*)(ws + 0);           // 32 MiB rotating
  unsigned short* hs_bf = (unsigned short*)(ws + 33554432);    // dead after qkv_a
  unsigned short* attnb = (unsigned short*)(ws + 33554432);    // reuse
  float* qkv_part = (float*)(ws + 50331648);                   // dead after rms
  unsigned short* kv_bf = (unsigned short*)(ws + 50331648);    // reuse (alive->attn)
  unsigned short* qa_bf = (unsigned short*)(ws + 138412032);
  unsigned short* ckv_bf = (unsigned short*)(ws + 144703488);
  unsigned short* qfullb = (unsigned short*)(ws + 147324928);  // alive->attn
  unsigned short* Vt = (unsigned short*)(ws + 172490752);      // alive->attn
  unsigned short* Kr = (unsigned short*)(ws + 189267968);      // 256 KiB

  dim3 blk(256);
  auto cvt = [&](const float* src, unsigned short* dst, size_t n) {
    int n8 = (int)(n / 8);
    cvt_kernel<<<(n8 + 255) / 256, blk, 0, stream>>>(src, dst, n8);
  };

  cvt(hs, hs_bf, (size_t)S_LEN * HDIM);
  // combined q_a || kv_a weights
  cvt(q_a_w, wslot, (size_t)RQ_ * HDIM);
  cvt(kv_a_w, wslot + (size_t)RQ_ * HDIM, (size_t)CKV_W * HDIM);
  // fused q_a + kv_a projection: N=2112, split-K=4 (1088 blocks)
  gemm_bf<false, true><<<dim3(17, S_LEN / 128, 4), blk, 0, stream>>>(
      hs_bf, HDIM, wslot, HDIM, qkv_part, NQKV, NQKV, HDIM / 4);
  // fused partial-sum + both RMS norms + Kr RoPE
  rms_fused<<<S_LEN, blk, 0, stream>>>(qkv_part, q_a_ln, kv_a_ln, freqs,
                                       qa_bf, ckv_bf, Kr);
  // q_b and kv_b weights -> wslot (q_b at 0, kv_b after)
  cvt(q_b_w, wslot, (size_t)QFW * RQ_);
  cvt(kv_b_w, wslot + (size_t)QFW * RQ_, (size_t)KVW * 512);
  // merged q_b + kv_b dispatch: 768 + 1024 = 1792 blocks
  gemm_dual<<<dim3(1792), blk, 0, stream>>>(
      qa_bf, RQ_, wslot, RQ_, qfullb, QFW, RQ_, 768,
      ckv_bf, 512, wslot + (size_t)QFW * RQ_, 512, kv_bf, KVW, 512, Vt);
  rope_q_kernel<<<(NHEAD * S_LEN * 32 + 255) / 256, blk, 0, stream>>>(qfullb, freqs);
  attn_kernel<<<dim3(1024), blk, 0, stream>>>(qfullb, kv_bf, Kr, Vt, attnb);
  cvt(o_w, wslot, (size_t)HDIM * HDIM);
  gemm_bf<false, false><<<dim3(HDIM / 128, S_LEN / 128), blk, 0, stream>>>(
      attnb, HDIM, wslot, HDIM, out, HDIM, HDIM, HDIM);
}

// Round 23
// 508.255 us; speedup vs baseline: 1.4746x; 1.0041x over previous
//
#include <hip/hip_runtime.h>
#define S_LEN 2048
#define HDIM 4096
#define NHEAD 32
#define QKD 192
#define RQ_ 1536
#define CKV_W 576
#define NQKV 2112
#define KVW 8192
#define QFW 6144
#define SC2F 0.1041216313667742f

typedef float f32x4 __attribute__((ext_vector_type(4)));
typedef __bf16 bf16x8 __attribute__((ext_vector_type(8)));

__device__ __forceinline__ unsigned short f2bf(float f) {
  unsigned int u = __float_as_uint(f);
  u += 0x7fffu + ((u >> 16) & 1u);
  return (unsigned short)(u >> 16);
}
__device__ __forceinline__ float b2f(unsigned short u) {
  return __uint_as_float((unsigned int)u << 16);
}
__device__ __forceinline__ float ex2(float x) { return exp2f(x); }

__device__ __forceinline__ void stage16(const void* g, void* lds_base, int lane) {
  __builtin_amdgcn_global_load_lds(
      (const __attribute__((address_space(1))) unsigned int*)g,
      (__attribute__((address_space(3))) unsigned int*)lds_base, 16, 0, 0);
}

__global__ __launch_bounds__(256) void cvt_kernel(
    const float* __restrict__ in, unsigned short* __restrict__ out, int n8) {
  int i = blockIdx.x * 256 + threadIdx.x;
  if (i >= n8) return;
  const float4* p = reinterpret_cast<const float4*>(in) + (size_t)i * 2;
  float4 a = p[0], b = p[1];
  unsigned long long lo = (unsigned long long)f2bf(a.x) | ((unsigned long long)f2bf(a.y) << 16)
      | ((unsigned long long)f2bf(a.z) << 32) | ((unsigned long long)f2bf(a.w) << 48);
  unsigned long long hi = (unsigned long long)f2bf(b.x) | ((unsigned long long)f2bf(b.y) << 16)
      | ((unsigned long long)f2bf(b.z) << 32) | ((unsigned long long)f2bf(b.w) << 48);
  unsigned long long* q = reinterpret_cast<unsigned long long*>(out) + (size_t)i * 2;
  q[0] = lo; q[1] = hi;
}

// BK=32 2-phase dbuf 128x128 GEMM, M-fast XCD decode (proven config).
template<bool BF16OUT, bool SPLITK>
__global__ __launch_bounds__(256) void gemm_bf(
    const unsigned short* __restrict__ A, int lda,
    const unsigned short* __restrict__ B, int ldb,
    void* __restrict__ Cv, int ldc, int N, int K) {
  __shared__ unsigned short As[2][4][128][8];
  __shared__ unsigned short Bs[2][4][128][8];
  const int tid = threadIdx.x, lane = tid & 63, w = tid >> 6;
  const int gx = (int)gridDim.x, gy = (int)gridDim.y;
  const int nwg = gx * gy;
  int lin = (int)blockIdx.y * gx + (int)blockIdx.x;
  if ((nwg & 7) == 0) lin = (lin & 7) * (nwg >> 3) + (lin >> 3);
  const int bm = (lin % gy) * 128, bn = (lin / gy) * 128;
  const int koff = SPLITK ? (int)blockIdx.z * K : 0;
  const int wr = (w >> 1) * 64, wc = (w & 1) * 64;
  const int lg = lane >> 4, lm = lane & 15;
  f32x4 acc[4][4] = {};
  const int arow = bm + lane;
  int brow = bn + lane; if (brow >= N) brow = N - 1;

  auto STAGE = [&](int buf, int k0) {
#pragma unroll
    for (int i = 0; i < 2; ++i) {
      stage16(A + (size_t)(arow + i * 64) * lda + koff + k0 + w * 8, &As[buf][w][i * 64][0], lane);
      int br2 = brow + i * 64; if (br2 >= N) br2 = N - 1;
      stage16(B + (size_t)br2 * ldb + koff + k0 + w * 8, &Bs[buf][w][i * 64][0], lane);
    }
  };
  STAGE(0, 0);
  __syncthreads();
  int cur = 0;
  for (int k0 = 0; k0 < K; k0 += 32) {
    if (k0 + 32 < K) STAGE(cur ^ 1, k0 + 32);
    bf16x8 af[4], bf[4];
#pragma unroll
    for (int i = 0; i < 4; ++i)
      af[i] = *reinterpret_cast<const bf16x8*>(&As[cur][lg][wr + i * 16 + lm][0]);
#pragma unroll
    for (int j = 0; j < 4; ++j)
      bf[j] = *reinterpret_cast<const bf16x8*>(&Bs[cur][lg][wc + j * 16 + lm][0]);
    __builtin_amdgcn_s_setprio(1);
#pragma unroll
    for (int i = 0; i < 4; ++i)
#pragma unroll
      for (int j = 0; j < 4; ++j)
        acc[i][j] = __builtin_amdgcn_mfma_f32_16x16x32_bf16(af[i], bf[j], acc[i][j], 0, 0, 0);
    __builtin_amdgcn_s_setprio(0);
    __syncthreads();
    cur ^= 1;
  }
  size_t zoff = SPLITK ? (size_t)blockIdx.z * S_LEN * N : 0;
#pragma unroll
  for (int i = 0; i < 4; ++i)
#pragma unroll
    for (int j = 0; j < 4; ++j)
#pragma unroll
      for (int r = 0; r < 4; ++r) {
        int row = bm + wr + i * 16 + lg * 4 + r;
        int col = bn + wc + j * 16 + lm;
        if (col < N) {
          if constexpr (BF16OUT)
            ((unsigned short*)Cv)[(size_t)row * ldc + col] = f2bf(acc[i][j][r]);
          else
            ((float*)Cv)[zoff + (size_t)row * ldc + col] = acc[i][j][r];
        }
      }
}

// q_b and kv_b in ONE dispatch (tail overlap).
__global__ __launch_bounds__(256) void gemm_dual(
    const unsigned short* __restrict__ A1, int lda1,
    const unsigned short* __restrict__ B1, int ldb1,
    unsigned short* __restrict__ C1, int ldc1, int K1, int nwg1,
    const unsigned short* __restrict__ A2, int lda2,
    const unsigned short* __restrict__ B2, int ldb2,
    unsigned short* __restrict__ C2, int ldc2, int K2,
    unsigned short* __restrict__ VtOut) {
  __shared__ unsigned short As[2][4][128][8];
  __shared__ unsigned short Bs[2][4][128][8];
  const int tid = threadIdx.x, lane = tid & 63, w = tid >> 6;
  const int raw = (int)blockIdx.x;
  const bool second = (raw >= nwg1);
  const int nwg = second ? ((int)gridDim.x - nwg1) : nwg1;
  int lin = second ? raw - nwg1 : raw;
  lin = (lin & 7) * (nwg >> 3) + (lin >> 3);
  const int gy = S_LEN / 128;
  const int bm = (lin % gy) * 128, bn = (lin / gy) * 128;
  const unsigned short* A = second ? A2 : A1;
  const unsigned short* B = second ? B2 : B1;
  unsigned short* C = second ? C2 : C1;
  const int lda = second ? lda2 : lda1;
  const int ldb = second ? ldb2 : ldb1;
  const int ldc = second ? ldc2 : ldc1;
  const int K = second ? K2 : K1;
  const int wr = (w >> 1) * 64, wc = (w & 1) * 64;
  const int lg = lane >> 4, lm = lane & 15;
  f32x4 acc[4][4] = {};
  const int arow = bm + lane;
  const int brow = bn + lane;

  auto STAGE = [&](int buf, int k0) {
#pragma unroll
    for (int i = 0; i < 2; ++i) {
      stage16(A + (size_t)(arow + i * 64) * lda + k0 + w * 8, &As[buf][w][i * 64][0], lane);
      stage16(B + (size_t)(brow + i * 64) * ldb + k0 + w * 8, &Bs[buf][w][i * 64][0], lane);
    }
  };
  STAGE(0, 0);
  __syncthreads();
  int cur = 0;
  for (int k0 = 0; k0 < K; k0 += 32) {
    if (k0 + 32 < K) STAGE(cur ^ 1, k0 + 32);
    bf16x8 af[4], bf[4];
#pragma unroll
    for (int i = 0; i < 4; ++i)
      af[i] = *reinterpret_cast<const bf16x8*>(&As[cur][lg][wr + i * 16 + lm][0]);
#pragma unroll
    for (int j = 0; j < 4; ++j)
      bf[j] = *reinterpret_cast<const bf16x8*>(&Bs[cur][lg][wc + j * 16 + lm][0]);
    __builtin_amdgcn_s_setprio(1);
#pragma unroll
    for (int i = 0; i < 4; ++i)
#pragma unroll
      for (int j = 0; j < 4; ++j)
        acc[i][j] = __builtin_amdgcn_mfma_f32_16x16x32_bf16(af[i], bf[j], acc[i][j], 0, 0, 0);
    __builtin_amdgcn_s_setprio(0);
    __syncthreads();
    cur ^= 1;
  }

  if (second && (bn & 128)) {
    const int h2 = bn >> 8;
#pragma unroll
    for (int i = 0; i < 4; ++i)
#pragma unroll
      for (int j = 0; j < 4; ++j) {
        int d = wc + j * 16 + lm;
        unsigned long long pk =
              (unsigned long long)f2bf(acc[i][j][0])
            | ((unsigned long long)f2bf(acc[i][j][1]) << 16)
            | ((unsigned long long)f2bf(acc[i][j][2]) << 32)
            | ((unsigned long long)f2bf(acc[i][j][3]) << 48);
        *reinterpret_cast<unsigned long long*>(
            VtOut + (size_t)(h2 * 128 + d) * S_LEN + bm + wr + i * 16 + lg * 4) = pk;
      }
    return;
  }
#pragma unroll
  for (int i = 0; i < 4; ++i)
#pragma unroll
    for (int j = 0; j < 4; ++j)
#pragma unroll
      for (int r = 0; r < 4; ++r) {
        int row = bm + wr + i * 16 + lg * 4 + r;
        int col = bn + wc + j * 16 + lm;
        C[(size_t)row * ldc + col] = f2bf(acc[i][j][r]);
      }
}

// Fused: sum 2 K-slice partials (2112 cols), both RMS norms + Kr RoPE.
__global__ __launch_bounds__(256) void rms_fused(
    const float* __restrict__ P, const float* __restrict__ wq,
    const float* __restrict__ wkv, const float* __restrict__ freqs,
    unsigned short* __restrict__ yq, unsigned short* __restrict__ ykv,
    unsigned short* __restrict__ Kr) {
  __shared__ float red[8];
  const int row = blockIdx.x, tid = threadIdx.x;
  const float* base = P + (size_t)row * NQKV;
  float xq[6]; float ssq = 0.f;
#pragma unroll
  for (int ii = 0; ii < 6; ++ii) {
    int j = tid + ii * 256;
    float v = 0.f;
#pragma unroll
    for (int z = 0; z < 2; ++z) v += base[(size_t)z * S_LEN * NQKV + j];
    xq[ii] = v; ssq += v * v;
  }
  const float* bkv = base + RQ_;
  float x0 = 0.f, x1 = 0.f, x2 = 0.f;
#pragma unroll
  for (int z = 0; z < 2; ++z) {
    const float* b = bkv + (size_t)z * S_LEN * NQKV;
    x0 += b[tid]; x1 += b[tid + 256];
    if (tid < 64) x2 += b[tid + 512];
  }
  float sskv = x0 * x0 + x1 * x1;
#pragma unroll
  for (int off = 1; off < 64; off <<= 1) {
    ssq += __shfl_xor(ssq, off, 64);
    sskv += __shfl_xor(sskv, off, 64);
  }
  if ((tid & 63) == 0) { red[tid >> 6] = ssq; red[4 + (tid >> 6)] = sskv; }
  __syncthreads();
  float sq = rsqrtf((red[0] + red[1] + red[2] + red[3]) / (float)RQ_ + 1e-6f);
  float skv = rsqrtf((red[4] + red[5] + red[6] + red[7]) / 512.0f + 1e-6f);
  unsigned short* q = yq + (size_t)row * RQ_;
#pragma unroll
  for (int ii = 0; ii < 6; ++ii) {
    int j = tid + ii * 256;
    q[j] = f2bf(xq[ii] * sq * wq[j]);
  }
  unsigned short* k = ykv + (size_t)row * 512;
  k[tid] = f2bf(x0 * skv * wkv[tid]);
  k[tid + 256] = f2bf(x1 * skv * wkv[tid + 256]);
  if (tid < 64) {
    float part = __shfl_xor(x2, 1, 64);
    int r = tid >> 1;
    float f = freqs[(size_t)row * 32 + r];
    float c = cosf(f), sn = sinf(f);
    float out = (tid & 1) ? (part * sn + x2 * c) : (x2 * c - part * sn);
    Kr[(size_t)row * 64 + tid] = f2bf(out);
  }
}

__global__ __launch_bounds__(256) void rope_q_kernel(
    unsigned short* __restrict__ qf, const float* __restrict__ freqs) {
  int idx = blockIdx.x * 256 + threadIdx.x;
  if (idx >= NHEAD * S_LEN * 32) return;
  int r = idx & 31, s = (idx >> 5) & (S_LEN - 1), h = idx >> 16;
  unsigned short* p = qf + (size_t)s * QFW + h * QKD + 128 + 2 * r;
  float xr = b2f(p[0]), xi = b2f(p[1]);
  float f = freqs[(size_t)s * 32 + r];
  float c = cosf(f), sn = sinf(f);
  *reinterpret_cast<unsigned int*>(p) =
      (unsigned int)f2bf(xr * c - xi * sn) | ((unsigned int)f2bf(xr * sn + xi * c) << 16);
}

__global__ __launch_bounds__(256, 3) void attn_kernel(
    const unsigned short* __restrict__ Qf,
    const unsigned short* __restrict__ KV,
    const unsigned short* __restrict__ Kr,
    const unsigned short* __restrict__ Vt,
    unsigned short* __restrict__ O) {
  __shared__ unsigned short Ks[2][32 * 192];
  __shared__ unsigned short Vs[2][128 * 32];
  __shared__ unsigned short Ps[4][16 * 32];
  const int tid = threadIdx.x, lane = tid & 63, w = tid >> 6;
  const int wg = (int)blockIdx.x;
  const int lin = (wg & 7) * 128 + (wg >> 3);
  const int h = lin >> 5;
  const int qt = 31 - (lin & 31);
  const int qr0 = qt * 64 + w * 16;
  const int lg = lane >> 4, lm = lane & 15, lm7 = lane & 7;
  const unsigned short* Qh = Qf + h * QKD;
  const int hoff = h * 256;
  const unsigned short* Vh = Vt + (size_t)h * 128 * S_LEN;

  bf16x8 qf[6];
#pragma unroll
  for (int f = 0; f < 6; ++f)
    qf[f] = *reinterpret_cast<const bf16x8*>(
        Qh + (size_t)(qr0 + lm) * QFW + f * 32 + lg * 8);

  f32x4 o[8] = {};
  float l[4] = {};

  auto STAGE = [&](int b, int kp) {
#pragma unroll
    for (int i = 0; i < 3; ++i) {
      int fb = (w * 3 + i) * 64 + lane;
      int row = fb / 24;
      int blk = fb - row * 24;
      int gb = (blk & ~7) | ((blk ^ row) & 7);
      const unsigned short* src = (blk < 16)
          ? KV + (size_t)(kp + row) * KVW + hoff + gb * 8
          : Kr + (size_t)(kp + row) * 64 + (gb - 16) * 8;
      stage16(src, &Ks[b][(w * 3 + i) * 512], lane);
    }
#pragma unroll
    for (int i = 0; i < 2; ++i) {
      int fb = (w * 2 + i) * 64 + lane;
      int row = fb >> 2;
      int blk = fb & 3;
      stage16(Vh + (size_t)row * S_LEN + kp + blk * 8, &Vs[b][(w * 2 + i) * 512], lane);
    }
  };

  const int ntiles = (qt + 1) * 2;
  STAGE(0, 0);
  __syncthreads();
  int buf = 0;
  for (int ti = 0; ti < ntiles; ++ti) {
    const int kp = ti * 32;
    if (ti + 1 < ntiles) STAGE(buf ^ 1, kp + 32);
    if (kp <= qr0 + 15) {
      f32x4 sc[2] = {};
      __builtin_amdgcn_s_setprio(1);
#pragma unroll
      for (int f = 0; f < 6; ++f)
#pragma unroll
        for (int c = 0; c < 2; ++c) {
          int blk = f * 4 + lg;
          int sb = (blk & ~7) | ((blk ^ lm7) & 7);
          bf16x8 kf = *reinterpret_cast<const bf16x8*>(&Ks[buf][(c * 16 + lm) * 192 + sb * 8]);
          sc[c] = __builtin_amdgcn_mfma_f32_16x16x32_bf16(qf[f], kf, sc[c], 0, 0, 0);
        }
      __builtin_amdgcn_s_setprio(0);
      const int rb = qr0 + lg * 4;
#pragma unroll
      for (int r = 0; r < 4; ++r) {
        const int row = rb + r;
        float v0 = fmaf(sc[0][r], SC2F, -32.f); if (kp + lm > row) v0 = -1e9f;
        float v1 = fmaf(sc[1][r], SC2F, -32.f); if (kp + 16 + lm > row) v1 = -1e9f;
        float p0 = ex2(v0), p1 = ex2(v1);
        l[r] += p0 + p1;
        int pr = lg * 4 + r;
        int s3 = pr & 3;
        int b0 = lm >> 3;
        unsigned short* pp = &Ps[w][pr * 32];
        pp[((b0 ^ s3) << 3) + lm7] = f2bf(p0);
        pp[(((2 + b0) ^ s3) << 3) + lm7] = f2bf(p1);
      }
      bf16x8 pa = *reinterpret_cast<const bf16x8*>(
          &Ps[w][lm * 32 + ((lg ^ (lm & 3)) << 3)]);
      __builtin_amdgcn_s_setprio(1);
#pragma unroll
      for (int d = 0; d < 8; ++d) {
        bf16x8 vf = *reinterpret_cast<const bf16x8*>(&Vs[buf][(d * 16 + lm) * 32 + lg * 8]);
        o[d] = __builtin_amdgcn_mfma_f32_16x16x32_bf16(pa, vf, o[d], 0, 0, 0);
      }
      __builtin_amdgcn_s_setprio(0);
    }
    __syncthreads();
    buf ^= 1;
  }
#pragma unroll
  for (int r = 0; r < 4; ++r) {
    float t = l[r];
#pragma unroll
    for (int off = 1; off < 16; off <<= 1) t += __shfl_xor(t, off, 16);
    float inv = 1.0f / t;
    int row = qr0 + lg * 4 + r;
#pragma unroll
    for (int d = 0; d < 8; ++d)
      O[(size_t)row * 4096 + h * 128 + d * 16 + lm] = f2bf(o[d][r] * inv);
  }
}

extern "C" void kernel_launch(void* const* d_in, const int* in_sizes, int n_in,
                              void* d_out, int out_size, void* d_ws, size_t ws_size,
                              hipStream_t stream) {
  const float* hs = (const float*)d_in[0];
  const float* freqs = (const float*)d_in[1];
  const float* q_a_w = (const float*)d_in[2];
  const float* q_a_ln = (const float*)d_in[3];
  const float* q_b_w = (const float*)d_in[4];
  const float* kv_a_w = (const float*)d_in[5];
  const float* kv_a_ln = (const float*)d_in[6];
  const float* kv_b_w = (const float*)d_in[7];
  const float* o_w = (const float*)d_in[8];
  float* out = (float*)d_out;

  char* ws = (char*)d_ws;
  unsigned short* wslot = (unsigned short*)(ws + 0);
  unsigned short* hs_bf = (unsigned short*)(ws + 33554432);
  unsigned short* attnb = (unsigned short*)(ws + 33554432);
  float* qkv_part = (float*)(ws + 50331648);
  unsigned short* kv_bf = (unsigned short*)(ws + 50331648);
  unsigned short* qa_bf = (unsigned short*)(ws + 138412032);
  unsigned short* ckv_bf = (unsigned short*)(ws + 144703488);
  unsigned short* qfullb = (unsigned short*)(ws + 147324928);
  unsigned short* Vt = (unsigned short*)(ws + 172490752);
  unsigned short* Kr = (unsigned short*)(ws + 189267968);

  dim3 blk(256);
  auto cvt = [&](const float* src, unsigned short* dst, size_t n) {
    int n8 = (int)(n / 8);
    cvt_kernel<<<(n8 + 255) / 256, blk, 0, stream>>>(src, dst, n8);
  };

  cvt(hs, hs_bf, (size_t)S_LEN * HDIM);
  cvt(q_a_w, wslot, (size_t)RQ_ * HDIM);
  cvt(kv_a_w, wslot + (size_t)RQ_ * HDIM, (size_t)CKV_W * HDIM);
  // fused q_a + kv_a projection: N=2112, split-K=2 (544 blocks, 2.1/CU)
  gemm_bf<false, true><<<dim3(17, S_LEN / 128, 2), blk, 0, stream>>>(
      hs_bf, HDIM, wslot, HDIM, qkv_part, NQKV, NQKV, HDIM / 2);
  rms_fused<<<S_LEN, blk, 0, stream>>>(qkv_part, q_a_ln, kv_a_ln, freqs,
                                       qa_bf, ckv_bf, Kr);
  cvt(q_b_w, wslot, (size_t)QFW * RQ_);
  cvt(kv_b_w, wslot + (size_t)QFW * RQ_, (size_t)KVW * 512);
  gemm_dual<<<dim3(1792), blk, 0, stream>>>(
      qa_bf, RQ_, wslot, RQ_, qfullb, QFW, RQ_, 768,
      ckv_bf, 512, wslot + (size_t)QFW * RQ_, 512, kv_bf, KVW, 512, Vt);
  rope_q_kernel<<<(NHEAD * S_LEN * 32 + 255) / 256, blk, 0, stream>>>(qfullb, freqs);
  attn_kernel<<<dim3(1024), blk, 0, stream>>>(qfullb, kv_bf, Kr, Vt, attnb);
  cvt(o_w, wslot, (size_t)HDIM * HDIM);
  gemm_bf<false, false><<<dim3(HDIM / 128, S_LEN / 128), blk, 0, stream>>>(
      attnb, HDIM, wslot, HDIM, out, HDIM, HDIM, HDIM);
}

// Round 24
// 505.418 us; speedup vs baseline: 1.4829x; 1.0056x over previous
//
#include <hip/hip_runtime.h>
#define S_LEN 2048
#define HDIM 4096
#define NHEAD 32
#define QKD 192
#define RQ_ 1536
#define CKV_W 576
#define NQKV 2112
#define KVW 8192
#define QFW 6144
#define SC2F 0.1041216313667742f

typedef float f32x4 __attribute__((ext_vector_type(4)));
typedef __bf16 bf16x8 __attribute__((ext_vector_type(8)));

__device__ __forceinline__ unsigned short f2bf(float f) {
  unsigned int u = __float_as_uint(f);
  u += 0x7fffu + ((u >> 16) & 1u);
  return (unsigned short)(u >> 16);
}
__device__ __forceinline__ float b2f(unsigned short u) {
  return __uint_as_float((unsigned int)u << 16);
}
__device__ __forceinline__ float ex2(float x) { return exp2f(x); }

__device__ __forceinline__ void stage16(const void* g, void* lds_base, int lane) {
  __builtin_amdgcn_global_load_lds(
      (const __attribute__((address_space(1))) unsigned int*)g,
      (__attribute__((address_space(3))) unsigned int*)lds_base, 16, 0, 0);
}

__global__ __launch_bounds__(256) void cvt_kernel(
    const float* __restrict__ in, unsigned short* __restrict__ out, int n8) {
  int i = blockIdx.x * 256 + threadIdx.x;
  if (i >= n8) return;
  const float4* p = reinterpret_cast<const float4*>(in) + (size_t)i * 2;
  float4 a = p[0], b = p[1];
  unsigned long long lo = (unsigned long long)f2bf(a.x) | ((unsigned long long)f2bf(a.y) << 16)
      | ((unsigned long long)f2bf(a.z) << 32) | ((unsigned long long)f2bf(a.w) << 48);
  unsigned long long hi = (unsigned long long)f2bf(b.x) | ((unsigned long long)f2bf(b.y) << 16)
      | ((unsigned long long)f2bf(b.z) << 32) | ((unsigned long long)f2bf(b.w) << 48);
  unsigned long long* q = reinterpret_cast<unsigned long long*>(out) + (size_t)i * 2;
  q[0] = lo; q[1] = hi;
}

// Two-source cvt: elements [0,n8_1) from src1, [n8_1,n8_tot) from src2,
// contiguous destination (one dispatch for a weight pair).
__global__ __launch_bounds__(256) void cvt2_kernel(
    const float* __restrict__ s1, int n8_1,
    const float* __restrict__ s2, unsigned short* __restrict__ out, int n8_tot) {
  int i = blockIdx.x * 256 + threadIdx.x;
  if (i >= n8_tot) return;
  const float4* p = (i < n8_1)
      ? reinterpret_cast<const float4*>(s1) + (size_t)i * 2
      : reinterpret_cast<const float4*>(s2) + (size_t)(i - n8_1) * 2;
  float4 a = p[0], b = p[1];
  unsigned long long lo = (unsigned long long)f2bf(a.x) | ((unsigned long long)f2bf(a.y) << 16)
      | ((unsigned long long)f2bf(a.z) << 32) | ((unsigned long long)f2bf(a.w) << 48);
  unsigned long long hi = (unsigned long long)f2bf(b.x) | ((unsigned long long)f2bf(b.y) << 16)
      | ((unsigned long long)f2bf(b.z) << 32) | ((unsigned long long)f2bf(b.w) << 48);
  unsigned long long* q = reinterpret_cast<unsigned long long*>(out) + (size_t)i * 2;
  q[0] = lo; q[1] = hi;
}

// BK=32 2-phase dbuf 128x128 GEMM, M-fast XCD decode (proven config).
template<bool BF16OUT, bool SPLITK>
__global__ __launch_bounds__(256) void gemm_bf(
    const unsigned short* __restrict__ A, int lda,
    const unsigned short* __restrict__ B, int ldb,
    void* __restrict__ Cv, int ldc, int N, int K) {
  __shared__ unsigned short As[2][4][128][8];
  __shared__ unsigned short Bs[2][4][128][8];
  const int tid = threadIdx.x, lane = tid & 63, w = tid >> 6;
  const int gx = (int)gridDim.x, gy = (int)gridDim.y;
  const int nwg = gx * gy;
  int lin = (int)blockIdx.y * gx + (int)blockIdx.x;
  if ((nwg & 7) == 0) lin = (lin & 7) * (nwg >> 3) + (lin >> 3);
  const int bm = (lin % gy) * 128, bn = (lin / gy) * 128;
  const int koff = SPLITK ? (int)blockIdx.z * K : 0;
  const int wr = (w >> 1) * 64, wc = (w & 1) * 64;
  const int lg = lane >> 4, lm = lane & 15;
  f32x4 acc[4][4] = {};
  const int arow = bm + lane;
  int brow = bn + lane; if (brow >= N) brow = N - 1;

  auto STAGE = [&](int buf, int k0) {
#pragma unroll
    for (int i = 0; i < 2; ++i) {
      stage16(A + (size_t)(arow + i * 64) * lda + koff + k0 + w * 8, &As[buf][w][i * 64][0], lane);
      int br2 = brow + i * 64; if (br2 >= N) br2 = N - 1;
      stage16(B + (size_t)br2 * ldb + koff + k0 + w * 8, &Bs[buf][w][i * 64][0], lane);
    }
  };
  STAGE(0, 0);
  __syncthreads();
  int cur = 0;
  for (int k0 = 0; k0 < K; k0 += 32) {
    if (k0 + 32 < K) STAGE(cur ^ 1, k0 + 32);
    bf16x8 af[4], bf[4];
#pragma unroll
    for (int i = 0; i < 4; ++i)
      af[i] = *reinterpret_cast<const bf16x8*>(&As[cur][lg][wr + i * 16 + lm][0]);
#pragma unroll
    for (int j = 0; j < 4; ++j)
      bf[j] = *reinterpret_cast<const bf16x8*>(&Bs[cur][lg][wc + j * 16 + lm][0]);
    __builtin_amdgcn_s_setprio(1);
#pragma unroll
    for (int i = 0; i < 4; ++i)
#pragma unroll
      for (int j = 0; j < 4; ++j)
        acc[i][j] = __builtin_amdgcn_mfma_f32_16x16x32_bf16(af[i], bf[j], acc[i][j], 0, 0, 0);
    __builtin_amdgcn_s_setprio(0);
    __syncthreads();
    cur ^= 1;
  }
  size_t zoff = SPLITK ? (size_t)blockIdx.z * S_LEN * N : 0;
#pragma unroll
  for (int i = 0; i < 4; ++i)
#pragma unroll
    for (int j = 0; j < 4; ++j)
#pragma unroll
      for (int r = 0; r < 4; ++r) {
        int row = bm + wr + i * 16 + lg * 4 + r;
        int col = bn + wc + j * 16 + lm;
        if (col < N) {
          if constexpr (BF16OUT)
            ((unsigned short*)Cv)[(size_t)row * ldc + col] = f2bf(acc[i][j][r]);
          else
            ((float*)Cv)[zoff + (size_t)row * ldc + col] = acc[i][j][r];
        }
      }
}

// q_b and kv_b in ONE dispatch (tail overlap).
__global__ __launch_bounds__(256) void gemm_dual(
    const unsigned short* __restrict__ A1, int lda1,
    const unsigned short* __restrict__ B1, int ldb1,
    unsigned short* __restrict__ C1, int ldc1, int K1, int nwg1,
    const unsigned short* __restrict__ A2, int lda2,
    const unsigned short* __restrict__ B2, int ldb2,
    unsigned short* __restrict__ C2, int ldc2, int K2,
    unsigned short* __restrict__ VtOut) {
  __shared__ unsigned short As[2][4][128][8];
  __shared__ unsigned short Bs[2][4][128][8];
  const int tid = threadIdx.x, lane = tid & 63, w = tid >> 6;
  const int raw = (int)blockIdx.x;
  const bool second = (raw >= nwg1);
  const int nwg = second ? ((int)gridDim.x - nwg1) : nwg1;
  int lin = second ? raw - nwg1 : raw;
  lin = (lin & 7) * (nwg >> 3) + (lin >> 3);
  const int gy = S_LEN / 128;
  const int bm = (lin % gy) * 128, bn = (lin / gy) * 128;
  const unsigned short* A = second ? A2 : A1;
  const unsigned short* B = second ? B2 : B1;
  unsigned short* C = second ? C2 : C1;
  const int lda = second ? lda2 : lda1;
  const int ldb = second ? ldb2 : ldb1;
  const int ldc = second ? ldc2 : ldc1;
  const int K = second ? K2 : K1;
  const int wr = (w >> 1) * 64, wc = (w & 1) * 64;
  const int lg = lane >> 4, lm = lane & 15;
  f32x4 acc[4][4] = {};
  const int arow = bm + lane;
  const int brow = bn + lane;

  auto STAGE = [&](int buf, int k0) {
#pragma unroll
    for (int i = 0; i < 2; ++i) {
      stage16(A + (size_t)(arow + i * 64) * lda + k0 + w * 8, &As[buf][w][i * 64][0], lane);
      stage16(B + (size_t)(brow + i * 64) * ldb + k0 + w * 8, &Bs[buf][w][i * 64][0], lane);
    }
  };
  STAGE(0, 0);
  __syncthreads();
  int cur = 0;
  for (int k0 = 0; k0 < K; k0 += 32) {
    if (k0 + 32 < K) STAGE(cur ^ 1, k0 + 32);
    bf16x8 af[4], bf[4];
#pragma unroll
    for (int i = 0; i < 4; ++i)
      af[i] = *reinterpret_cast<const bf16x8*>(&As[cur][lg][wr + i * 16 + lm][0]);
#pragma unroll
    for (int j = 0; j < 4; ++j)
      bf[j] = *reinterpret_cast<const bf16x8*>(&Bs[cur][lg][wc + j * 16 + lm][0]);
    __builtin_amdgcn_s_setprio(1);
#pragma unroll
    for (int i = 0; i < 4; ++i)
#pragma unroll
      for (int j = 0; j < 4; ++j)
        acc[i][j] = __builtin_amdgcn_mfma_f32_16x16x32_bf16(af[i], bf[j], acc[i][j], 0, 0, 0);
    __builtin_amdgcn_s_setprio(0);
    __syncthreads();
    cur ^= 1;
  }

  if (second && (bn & 128)) {
    const int h2 = bn >> 8;
#pragma unroll
    for (int i = 0; i < 4; ++i)
#pragma unroll
      for (int j = 0; j < 4; ++j) {
        int d = wc + j * 16 + lm;
        unsigned long long pk =
              (unsigned long long)f2bf(acc[i][j][0])
            | ((unsigned long long)f2bf(acc[i][j][1]) << 16)
            | ((unsigned long long)f2bf(acc[i][j][2]) << 32)
            | ((unsigned long long)f2bf(acc[i][j][3]) << 48);
        *reinterpret_cast<unsigned long long*>(
            VtOut + (size_t)(h2 * 128 + d) * S_LEN + bm + wr + i * 16 + lg * 4) = pk;
      }
    return;
  }
#pragma unroll
  for (int i = 0; i < 4; ++i)
#pragma unroll
    for (int j = 0; j < 4; ++j)
#pragma unroll
      for (int r = 0; r < 4; ++r) {
        int row = bm + wr + i * 16 + lg * 4 + r;
        int col = bn + wc + j * 16 + lm;
        C[(size_t)row * ldc + col] = f2bf(acc[i][j][r]);
      }
}

// Fused: sum 2 K-slice partials (2112 cols), both RMS norms + Kr RoPE.
__global__ __launch_bounds__(256) void rms_fused(
    const float* __restrict__ P, const float* __restrict__ wq,
    const float* __restrict__ wkv, const float* __restrict__ freqs,
    unsigned short* __restrict__ yq, unsigned short* __restrict__ ykv,
    unsigned short* __restrict__ Kr) {
  __shared__ float red[8];
  const int row = blockIdx.x, tid = threadIdx.x;
  const float* base = P + (size_t)row * NQKV;
  float xq[6]; float ssq = 0.f;
#pragma unroll
  for (int ii = 0; ii < 6; ++ii) {
    int j = tid + ii * 256;
    float v = 0.f;
#pragma unroll
    for (int z = 0; z < 2; ++z) v += base[(size_t)z * S_LEN * NQKV + j];
    xq[ii] = v; ssq += v * v;
  }
  const float* bkv = base + RQ_;
  float x0 = 0.f, x1 = 0.f, x2 = 0.f;
#pragma unroll
  for (int z = 0; z < 2; ++z) {
    const float* b = bkv + (size_t)z * S_LEN * NQKV;
    x0 += b[tid]; x1 += b[tid + 256];
    if (tid < 64) x2 += b[tid + 512];
  }
  float sskv = x0 * x0 + x1 * x1;
#pragma unroll
  for (int off = 1; off < 64; off <<= 1) {
    ssq += __shfl_xor(ssq, off, 64);
    sskv += __shfl_xor(sskv, off, 64);
  }
  if ((tid & 63) == 0) { red[tid >> 6] = ssq; red[4 + (tid >> 6)] = sskv; }
  __syncthreads();
  float sq = rsqrtf((red[0] + red[1] + red[2] + red[3]) / (float)RQ_ + 1e-6f);
  float skv = rsqrtf((red[4] + red[5] + red[6] + red[7]) / 512.0f + 1e-6f);
  unsigned short* q = yq + (size_t)row * RQ_;
#pragma unroll
  for (int ii = 0; ii < 6; ++ii) {
    int j = tid + ii * 256;
    q[j] = f2bf(xq[ii] * sq * wq[j]);
  }
  unsigned short* k = ykv + (size_t)row * 512;
  k[tid] = f2bf(x0 * skv * wkv[tid]);
  k[tid + 256] = f2bf(x1 * skv * wkv[tid + 256]);
  if (tid < 64) {
    float part = __shfl_xor(x2, 1, 64);
    int r = tid >> 1;
    float f = freqs[(size_t)row * 32 + r];
    float c = cosf(f), sn = sinf(f);
    float out = (tid & 1) ? (part * sn + x2 * c) : (x2 * c - part * sn);
    Kr[(size_t)row * 64 + tid] = f2bf(out);
  }
}

__global__ __launch_bounds__(256) void rope_q_kernel(
    unsigned short* __restrict__ qf, const float* __restrict__ freqs) {
  int idx = blockIdx.x * 256 + threadIdx.x;
  if (idx >= NHEAD * S_LEN * 32) return;
  int r = idx & 31, s = (idx >> 5) & (S_LEN - 1), h = idx >> 16;
  unsigned short* p = qf + (size_t)s * QFW + h * QKD + 128 + 2 * r;
  float xr = b2f(p[0]), xi = b2f(p[1]);
  float f = freqs[(size_t)s * 32 + r];
  float c = cosf(f), sn = sinf(f);
  *reinterpret_cast<unsigned int*>(p) =
      (unsigned int)f2bf(xr * c - xi * sn) | ((unsigned int)f2bf(xr * sn + xi * c) << 16);
}

__global__ __launch_bounds__(256, 3) void attn_kernel(
    const unsigned short* __restrict__ Qf,
    const unsigned short* __restrict__ KV,
    const unsigned short* __restrict__ Kr,
    const unsigned short* __restrict__ Vt,
    unsigned short* __restrict__ O) {
  __shared__ unsigned short Ks[2][32 * 192];
  __shared__ unsigned short Vs[2][128 * 32];
  __shared__ unsigned short Ps[4][16 * 32];
  const int tid = threadIdx.x, lane = tid & 63, w = tid >> 6;
  const int wg = (int)blockIdx.x;
  const int lin = (wg & 7) * 128 + (wg >> 3);
  const int h = lin >> 5;
  const int qt = 31 - (lin & 31);
  const int qr0 = qt * 64 + w * 16;
  const int lg = lane >> 4, lm = lane & 15, lm7 = lane & 7;
  const unsigned short* Qh = Qf + h * QKD;
  const int hoff = h * 256;
  const unsigned short* Vh = Vt + (size_t)h * 128 * S_LEN;

  bf16x8 qf[6];
#pragma unroll
  for (int f = 0; f < 6; ++f)
    qf[f] = *reinterpret_cast<const bf16x8*>(
        Qh + (size_t)(qr0 + lm) * QFW + f * 32 + lg * 8);

  f32x4 o[8] = {};
  float l[4] = {};

  auto STAGE = [&](int b, int kp) {
#pragma unroll
    for (int i = 0; i < 3; ++i) {
      int fb = (w * 3 + i) * 64 + lane;
      int row = fb / 24;
      int blk = fb - row * 24;
      int gb = (blk & ~7) | ((blk ^ row) & 7);
      const unsigned short* src = (blk < 16)
          ? KV + (size_t)(kp + row) * KVW + hoff + gb * 8
          : Kr + (size_t)(kp + row) * 64 + (gb - 16) * 8;
      stage16(src, &Ks[b][(w * 3 + i) * 512], lane);
    }
#pragma unroll
    for (int i = 0; i < 2; ++i) {
      int fb = (w * 2 + i) * 64 + lane;
      int row = fb >> 2;
      int blk = fb & 3;
      stage16(Vh + (size_t)row * S_LEN + kp + blk * 8, &Vs[b][(w * 2 + i) * 512], lane);
    }
  };

  const int ntiles = (qt + 1) * 2;
  STAGE(0, 0);
  __syncthreads();
  int buf = 0;
  for (int ti = 0; ti < ntiles; ++ti) {
    const int kp = ti * 32;
    if (ti + 1 < ntiles) STAGE(buf ^ 1, kp + 32);
    if (kp <= qr0 + 15) {
      f32x4 sc[2] = {};
      __builtin_amdgcn_s_setprio(1);
#pragma unroll
      for (int f = 0; f < 6; ++f)
#pragma unroll
        for (int c = 0; c < 2; ++c) {
          int blk = f * 4 + lg;
          int sb = (blk & ~7) | ((blk ^ lm7) & 7);
          bf16x8 kf = *reinterpret_cast<const bf16x8*>(&Ks[buf][(c * 16 + lm) * 192 + sb * 8]);
          sc[c] = __builtin_amdgcn_mfma_f32_16x16x32_bf16(qf[f], kf, sc[c], 0, 0, 0);
        }
      __builtin_amdgcn_s_setprio(0);
      const int rb = qr0 + lg * 4;
#pragma unroll
      for (int r = 0; r < 4; ++r) {
        const int row = rb + r;
        float v0 = fmaf(sc[0][r], SC2F, -32.f); if (kp + lm > row) v0 = -1e9f;
        float v1 = fmaf(sc[1][r], SC2F, -32.f); if (kp + 16 + lm > row) v1 = -1e9f;
        float p0 = ex2(v0), p1 = ex2(v1);
        l[r] += p0 + p1;
        int pr = lg * 4 + r;
        int s3 = pr & 3;
        int b0 = lm >> 3;
        unsigned short* pp = &Ps[w][pr * 32];
        pp[((b0 ^ s3) << 3) + lm7] = f2bf(p0);
        pp[(((2 + b0) ^ s3) << 3) + lm7] = f2bf(p1);
      }
      bf16x8 pa = *reinterpret_cast<const bf16x8*>(
          &Ps[w][lm * 32 + ((lg ^ (lm & 3)) << 3)]);
      __builtin_amdgcn_s_setprio(1);
#pragma unroll
      for (int d = 0; d < 8; ++d) {
        bf16x8 vf = *reinterpret_cast<const bf16x8*>(&Vs[buf][(d * 16 + lm) * 32 + lg * 8]);
        o[d] = __builtin_amdgcn_mfma_f32_16x16x32_bf16(pa, vf, o[d], 0, 0, 0);
      }
      __builtin_amdgcn_s_setprio(0);
    }
    __syncthreads();
    buf ^= 1;
  }
#pragma unroll
  for (int r = 0; r < 4; ++r) {
    float t = l[r];
#pragma unroll
    for (int off = 1; off < 16; off <<= 1) t += __shfl_xor(t, off, 16);
    float inv = 1.0f / t;
    int row = qr0 + lg * 4 + r;
#pragma unroll
    for (int d = 0; d < 8; ++d)
      O[(size_t)row * 4096 + h * 128 + d * 16 + lm] = f2bf(o[d][r] * inv);
  }
}

extern "C" void kernel_launch(void* const* d_in, const int* in_sizes, int n_in,
                              void* d_out, int out_size, void* d_ws, size_t ws_size,
                              hipStream_t stream) {
  const float* hs = (const float*)d_in[0];
  const float* freqs = (const float*)d_in[1];
  const float* q_a_w = (const float*)d_in[2];
  const float* q_a_ln = (const float*)d_in[3];
  const float* q_b_w = (const float*)d_in[4];
  const float* kv_a_w = (const float*)d_in[5];
  const float* kv_a_ln = (const float*)d_in[6];
  const float* kv_b_w = (const float*)d_in[7];
  const float* o_w = (const float*)d_in[8];
  float* out = (float*)d_out;

  char* ws = (char*)d_ws;
  unsigned short* wslot = (unsigned short*)(ws + 0);
  unsigned short* hs_bf = (unsigned short*)(ws + 33554432);
  unsigned short* attnb = (unsigned short*)(ws + 33554432);
  float* qkv_part = (float*)(ws + 50331648);
  unsigned short* kv_bf = (unsigned short*)(ws + 50331648);
  unsigned short* qa_bf = (unsigned short*)(ws + 138412032);
  unsigned short* ckv_bf = (unsigned short*)(ws + 144703488);
  unsigned short* qfullb = (unsigned short*)(ws + 147324928);
  unsigned short* Vt = (unsigned short*)(ws + 172490752);
  unsigned short* Kr = (unsigned short*)(ws + 189267968);

  dim3 blk(256);
  auto cvt = [&](const float* src, unsigned short* dst, size_t n) {
    int n8 = (int)(n / 8);
    cvt_kernel<<<(n8 + 255) / 256, blk, 0, stream>>>(src, dst, n8);
  };
  auto cvt2 = [&](const float* s1, size_t n1, const float* s2, size_t n2,
                  unsigned short* dst) {
    int n8_1 = (int)(n1 / 8), n8_t = (int)((n1 + n2) / 8);
    cvt2_kernel<<<(n8_t + 255) / 256, blk, 0, stream>>>(s1, n8_1, s2, dst, n8_t);
  };

  cvt(hs, hs_bf, (size_t)S_LEN * HDIM);
  // q_a || kv_a weights in one dispatch
  cvt2(q_a_w, (size_t)RQ_ * HDIM, kv_a_w, (size_t)CKV_W * HDIM, wslot);
  // fused q_a + kv_a projection: N=2112, split-K=2 (544 blocks)
  gemm_bf<false, true><<<dim3(17, S_LEN / 128, 2), blk, 0, stream>>>(
      hs_bf, HDIM, wslot, HDIM, qkv_part, NQKV, NQKV, HDIM / 2);
  rms_fused<<<S_LEN, blk, 0, stream>>>(qkv_part, q_a_ln, kv_a_ln, freqs,
                                       qa_bf, ckv_bf, Kr);
  // q_b || kv_b weights in one dispatch
  cvt2(q_b_w, (size_t)QFW * RQ_, kv_b_w, (size_t)KVW * 512, wslot);
  gemm_dual<<<dim3(1792), blk, 0, stream>>>(
      qa_bf, RQ_, wslot, RQ_, qfullb, QFW, RQ_, 768,
      ckv_bf, 512, wslot + (size_t)QFW * RQ_, 512, kv_bf, KVW, 512, Vt);
  rope_q_kernel<<<(NHEAD * S_LEN * 32 + 255) / 256, blk, 0, stream>>>(qfullb, freqs);
  attn_kernel<<<dim3(1024), blk, 0, stream>>>(qfullb, kv_bf, Kr, Vt, attnb);
  cvt(o_w, wslot, (size_t)HDIM * HDIM);
  gemm_bf<false, false><<<dim3(HDIM / 128, S_LEN / 128), blk, 0, stream>>>(
      attnb, HDIM, wslot, HDIM, out, HDIM, HDIM, HDIM);
}

// Round 25
// 501.942 us; speedup vs baseline: 1.4931x; 1.0069x over previous
//
#include <hip/hip_runtime.h>
#define S_LEN 2048
#define HDIM 4096
#define NHEAD 32
#define QKD 192
#define RQ_ 1536
#define CKV_W 576
#define NQKV 2112
#define KVW 8192
#define QFW 6144
#define SC2F 0.1041216313667742f

typedef float f32x4 __attribute__((ext_vector_type(4)));
typedef __bf16 bf16x8 __attribute__((ext_vector_type(8)));

__device__ __forceinline__ unsigned short f2bf(float f) {
  unsigned int u = __float_as_uint(f);
  u += 0x7fffu + ((u >> 16) & 1u);
  return (unsigned short)(u >> 16);
}
__device__ __forceinline__ float b2f(unsigned short u) {
  return __uint_as_float((unsigned int)u << 16);
}
__device__ __forceinline__ float ex2(float x) { return exp2f(x); }

__device__ __forceinline__ void stage16(const void* g, void* lds_base, int lane) {
  __builtin_amdgcn_global_load_lds(
      (const __attribute__((address_space(1))) unsigned int*)g,
      (__attribute__((address_space(3))) unsigned int*)lds_base, 16, 0, 0);
}

__global__ __launch_bounds__(256) void cvt_kernel(
    const float* __restrict__ in, unsigned short* __restrict__ out, int n8) {
  int i = blockIdx.x * 256 + threadIdx.x;
  if (i >= n8) return;
  const float4* p = reinterpret_cast<const float4*>(in) + (size_t)i * 2;
  float4 a = p[0], b = p[1];
  unsigned long long lo = (unsigned long long)f2bf(a.x) | ((unsigned long long)f2bf(a.y) << 16)
      | ((unsigned long long)f2bf(a.z) << 32) | ((unsigned long long)f2bf(a.w) << 48);
  unsigned long long hi = (unsigned long long)f2bf(b.x) | ((unsigned long long)f2bf(b.y) << 16)
      | ((unsigned long long)f2bf(b.z) << 32) | ((unsigned long long)f2bf(b.w) << 48);
  unsigned long long* q = reinterpret_cast<unsigned long long*>(out) + (size_t)i * 2;
  q[0] = lo; q[1] = hi;
}

// Two-source cvt: one dispatch for a weight pair, contiguous dest.
__global__ __launch_bounds__(256) void cvt2_kernel(
    const float* __restrict__ s1, int n8_1,
    const float* __restrict__ s2, unsigned short* __restrict__ out, int n8_tot) {
  int i = blockIdx.x * 256 + threadIdx.x;
  if (i >= n8_tot) return;
  const float4* p = (i < n8_1)
      ? reinterpret_cast<const float4*>(s1) + (size_t)i * 2
      : reinterpret_cast<const float4*>(s2) + (size_t)(i - n8_1) * 2;
  float4 a = p[0], b = p[1];
  unsigned long long lo = (unsigned long long)f2bf(a.x) | ((unsigned long long)f2bf(a.y) << 16)
      | ((unsigned long long)f2bf(a.z) << 32) | ((unsigned long long)f2bf(a.w) << 48);
  unsigned long long hi = (unsigned long long)f2bf(b.x) | ((unsigned long long)f2bf(b.y) << 16)
      | ((unsigned long long)f2bf(b.z) << 32) | ((unsigned long long)f2bf(b.w) << 48);
  unsigned long long* q = reinterpret_cast<unsigned long long*>(out) + (size_t)i * 2;
  q[0] = lo; q[1] = hi;
}

// BK=32 2-phase dbuf 128x128 GEMM, M-fast XCD decode (proven config).
template<bool BF16OUT, bool SPLITK>
__global__ __launch_bounds__(256) void gemm_bf(
    const unsigned short* __restrict__ A, int lda,
    const unsigned short* __restrict__ B, int ldb,
    void* __restrict__ Cv, int ldc, int N, int K) {
  __shared__ unsigned short As[2][4][128][8];
  __shared__ unsigned short Bs[2][4][128][8];
  const int tid = threadIdx.x, lane = tid & 63, w = tid >> 6;
  const int gx = (int)gridDim.x, gy = (int)gridDim.y;
  const int nwg = gx * gy;
  int lin = (int)blockIdx.y * gx + (int)blockIdx.x;
  if ((nwg & 7) == 0) lin = (lin & 7) * (nwg >> 3) + (lin >> 3);
  const int bm = (lin % gy) * 128, bn = (lin / gy) * 128;
  const int koff = SPLITK ? (int)blockIdx.z * K : 0;
  const int wr = (w >> 1) * 64, wc = (w & 1) * 64;
  const int lg = lane >> 4, lm = lane & 15;
  f32x4 acc[4][4] = {};
  const int arow = bm + lane;
  int brow = bn + lane; if (brow >= N) brow = N - 1;

  auto STAGE = [&](int buf, int k0) {
#pragma unroll
    for (int i = 0; i < 2; ++i) {
      stage16(A + (size_t)(arow + i * 64) * lda + koff + k0 + w * 8, &As[buf][w][i * 64][0], lane);
      int br2 = brow + i * 64; if (br2 >= N) br2 = N - 1;
      stage16(B + (size_t)br2 * ldb + koff + k0 + w * 8, &Bs[buf][w][i * 64][0], lane);
    }
  };
  STAGE(0, 0);
  __syncthreads();
  int cur = 0;
  for (int k0 = 0; k0 < K; k0 += 32) {
    if (k0 + 32 < K) STAGE(cur ^ 1, k0 + 32);
    bf16x8 af[4], bf[4];
#pragma unroll
    for (int i = 0; i < 4; ++i)
      af[i] = *reinterpret_cast<const bf16x8*>(&As[cur][lg][wr + i * 16 + lm][0]);
#pragma unroll
    for (int j = 0; j < 4; ++j)
      bf[j] = *reinterpret_cast<const bf16x8*>(&Bs[cur][lg][wc + j * 16 + lm][0]);
    __builtin_amdgcn_s_setprio(1);
#pragma unroll
    for (int i = 0; i < 4; ++i)
#pragma unroll
      for (int j = 0; j < 4; ++j)
        acc[i][j] = __builtin_amdgcn_mfma_f32_16x16x32_bf16(af[i], bf[j], acc[i][j], 0, 0, 0);
    __builtin_amdgcn_s_setprio(0);
    __syncthreads();
    cur ^= 1;
  }
  size_t zoff = SPLITK ? (size_t)blockIdx.z * S_LEN * N : 0;
#pragma unroll
  for (int i = 0; i < 4; ++i)
#pragma unroll
    for (int j = 0; j < 4; ++j)
#pragma unroll
      for (int r = 0; r < 4; ++r) {
        int row = bm + wr + i * 16 + lg * 4 + r;
        int col = bn + wc + j * 16 + lm;
        if (col < N) {
          if constexpr (BF16OUT)
            ((unsigned short*)Cv)[(size_t)row * ldc + col] = f2bf(acc[i][j][r]);
          else
            ((float*)Cv)[zoff + (size_t)row * ldc + col] = acc[i][j][r];
        }
      }
}

// q_b and kv_b in ONE dispatch + tail cvt segment (o_w f32->bf16 hidden in
// the GEMM's idle memory slots).
__global__ __launch_bounds__(256) void gemm_dual(
    const unsigned short* __restrict__ A1, int lda1,
    const unsigned short* __restrict__ B1, int ldb1,
    unsigned short* __restrict__ C1, int ldc1, int K1, int nwg1,
    const unsigned short* __restrict__ A2, int lda2,
    const unsigned short* __restrict__ B2, int ldb2,
    unsigned short* __restrict__ C2, int ldc2, int K2, int nwg2,
    unsigned short* __restrict__ VtOut,
    const float* __restrict__ cvt_src, unsigned short* __restrict__ cvt_dst,
    int n8cvt) {
  const int tid = threadIdx.x;
  const int raw = (int)blockIdx.x;

  if (raw >= nwg1 + nwg2) {   // ---- cvt segment: pure streaming ----
    const int ncvt = (int)gridDim.x - nwg1 - nwg2;
    const int stride = ncvt * 256;
    for (int i = (raw - nwg1 - nwg2) * 256 + tid; i < n8cvt; i += stride) {
      const float4* p = reinterpret_cast<const float4*>(cvt_src) + (size_t)i * 2;
      float4 a = p[0], b = p[1];
      unsigned long long lo = (unsigned long long)f2bf(a.x) | ((unsigned long long)f2bf(a.y) << 16)
          | ((unsigned long long)f2bf(a.z) << 32) | ((unsigned long long)f2bf(a.w) << 48);
      unsigned long long hi = (unsigned long long)f2bf(b.x) | ((unsigned long long)f2bf(b.y) << 16)
          | ((unsigned long long)f2bf(b.z) << 32) | ((unsigned long long)f2bf(b.w) << 48);
      unsigned long long* q = reinterpret_cast<unsigned long long*>(cvt_dst) + (size_t)i * 2;
      q[0] = lo; q[1] = hi;
    }
    return;
  }

  __shared__ unsigned short As[2][4][128][8];
  __shared__ unsigned short Bs[2][4][128][8];
  const int lane = tid & 63, w = tid >> 6;
  const bool second = (raw >= nwg1);
  const int nwg = second ? nwg2 : nwg1;
  int lin = second ? raw - nwg1 : raw;
  lin = (lin & 7) * (nwg >> 3) + (lin >> 3);
  const int gy = S_LEN / 128;
  const int bm = (lin % gy) * 128, bn = (lin / gy) * 128;
  const unsigned short* A = second ? A2 : A1;
  const unsigned short* B = second ? B2 : B1;
  unsigned short* C = second ? C2 : C1;
  const int lda = second ? lda2 : lda1;
  const int ldb = second ? ldb2 : ldb1;
  const int ldc = second ? ldc2 : ldc1;
  const int K = second ? K2 : K1;
  const int wr = (w >> 1) * 64, wc = (w & 1) * 64;
  const int lg = lane >> 4, lm = lane & 15;
  f32x4 acc[4][4] = {};
  const int arow = bm + lane;
  const int brow = bn + lane;

  auto STAGE = [&](int buf, int k0) {
#pragma unroll
    for (int i = 0; i < 2; ++i) {
      stage16(A + (size_t)(arow + i * 64) * lda + k0 + w * 8, &As[buf][w][i * 64][0], lane);
      stage16(B + (size_t)(brow + i * 64) * ldb + k0 + w * 8, &Bs[buf][w][i * 64][0], lane);
    }
  };
  STAGE(0, 0);
  __syncthreads();
  int cur = 0;
  for (int k0 = 0; k0 < K; k0 += 32) {
    if (k0 + 32 < K) STAGE(cur ^ 1, k0 + 32);
    bf16x8 af[4], bf[4];
#pragma unroll
    for (int i = 0; i < 4; ++i)
      af[i] = *reinterpret_cast<const bf16x8*>(&As[cur][lg][wr + i * 16 + lm][0]);
#pragma unroll
    for (int j = 0; j < 4; ++j)
      bf[j] = *reinterpret_cast<const bf16x8*>(&Bs[cur][lg][wc + j * 16 + lm][0]);
    __builtin_amdgcn_s_setprio(1);
#pragma unroll
    for (int i = 0; i < 4; ++i)
#pragma unroll
      for (int j = 0; j < 4; ++j)
        acc[i][j] = __builtin_amdgcn_mfma_f32_16x16x32_bf16(af[i], bf[j], acc[i][j], 0, 0, 0);
    __builtin_amdgcn_s_setprio(0);
    __syncthreads();
    cur ^= 1;
  }

  if (second && (bn & 128)) {
    const int h2 = bn >> 8;
#pragma unroll
    for (int i = 0; i < 4; ++i)
#pragma unroll
      for (int j = 0; j < 4; ++j) {
        int d = wc + j * 16 + lm;
        unsigned long long pk =
              (unsigned long long)f2bf(acc[i][j][0])
            | ((unsigned long long)f2bf(acc[i][j][1]) << 16)
            | ((unsigned long long)f2bf(acc[i][j][2]) << 32)
            | ((unsigned long long)f2bf(acc[i][j][3]) << 48);
        *reinterpret_cast<unsigned long long*>(
            VtOut + (size_t)(h2 * 128 + d) * S_LEN + bm + wr + i * 16 + lg * 4) = pk;
      }
    return;
  }
#pragma unroll
  for (int i = 0; i < 4; ++i)
#pragma unroll
    for (int j = 0; j < 4; ++j)
#pragma unroll
      for (int r = 0; r < 4; ++r) {
        int row = bm + wr + i * 16 + lg * 4 + r;
        int col = bn + wc + j * 16 + lm;
        C[(size_t)row * ldc + col] = f2bf(acc[i][j][r]);
      }
}

// Fused: sum 2 K-slice partials (2112 cols), both RMS norms + Kr RoPE.
__global__ __launch_bounds__(256) void rms_fused(
    const float* __restrict__ P, const float* __restrict__ wq,
    const float* __restrict__ wkv, const float* __restrict__ freqs,
    unsigned short* __restrict__ yq, unsigned short* __restrict__ ykv,
    unsigned short* __restrict__ Kr) {
  __shared__ float red[8];
  const int row = blockIdx.x, tid = threadIdx.x;
  const float* base = P + (size_t)row * NQKV;
  float xq[6]; float ssq = 0.f;
#pragma unroll
  for (int ii = 0; ii < 6; ++ii) {
    int j = tid + ii * 256;
    float v = 0.f;
#pragma unroll
    for (int z = 0; z < 2; ++z) v += base[(size_t)z * S_LEN * NQKV + j];
    xq[ii] = v; ssq += v * v;
  }
  const float* bkv = base + RQ_;
  float x0 = 0.f, x1 = 0.f, x2 = 0.f;
#pragma unroll
  for (int z = 0; z < 2; ++z) {
    const float* b = bkv + (size_t)z * S_LEN * NQKV;
    x0 += b[tid]; x1 += b[tid + 256];
    if (tid < 64) x2 += b[tid + 512];
  }
  float sskv = x0 * x0 + x1 * x1;
#pragma unroll
  for (int off = 1; off < 64; off <<= 1) {
    ssq += __shfl_xor(ssq, off, 64);
    sskv += __shfl_xor(sskv, off, 64);
  }
  if ((tid & 63) == 0) { red[tid >> 6] = ssq; red[4 + (tid >> 6)] = sskv; }
  __syncthreads();
  float sq = rsqrtf((red[0] + red[1] + red[2] + red[3]) / (float)RQ_ + 1e-6f);
  float skv = rsqrtf((red[4] + red[5] + red[6] + red[7]) / 512.0f + 1e-6f);
  unsigned short* q = yq + (size_t)row * RQ_;
#pragma unroll
  for (int ii = 0; ii < 6; ++ii) {
    int j = tid + ii * 256;
    q[j] = f2bf(xq[ii] * sq * wq[j]);
  }
  unsigned short* k = ykv + (size_t)row * 512;
  k[tid] = f2bf(x0 * skv * wkv[tid]);
  k[tid + 256] = f2bf(x1 * skv * wkv[tid + 256]);
  if (tid < 64) {
    float part = __shfl_xor(x2, 1, 64);
    int r = tid >> 1;
    float f = freqs[(size_t)row * 32 + r];
    float c = cosf(f), sn = sinf(f);
    float out = (tid & 1) ? (part * sn + x2 * c) : (x2 * c - part * sn);
    Kr[(size_t)row * 64 + tid] = f2bf(out);
  }
}

__global__ __launch_bounds__(256) void rope_q_kernel(
    unsigned short* __restrict__ qf, const float* __restrict__ freqs) {
  int idx = blockIdx.x * 256 + threadIdx.x;
  if (idx >= NHEAD * S_LEN * 32) return;
  int r = idx & 31, s = (idx >> 5) & (S_LEN - 1), h = idx >> 16;
  unsigned short* p = qf + (size_t)s * QFW + h * QKD + 128 + 2 * r;
  float xr = b2f(p[0]), xi = b2f(p[1]);
  float f = freqs[(size_t)s * 32 + r];
  float c = cosf(f), sn = sinf(f);
  *reinterpret_cast<unsigned int*>(p) =
      (unsigned int)f2bf(xr * c - xi * sn) | ((unsigned int)f2bf(xr * sn + xi * c) << 16);
}

__global__ __launch_bounds__(256, 3) void attn_kernel(
    const unsigned short* __restrict__ Qf,
    const unsigned short* __restrict__ KV,
    const unsigned short* __restrict__ Kr,
    const unsigned short* __restrict__ Vt,
    unsigned short* __restrict__ O) {
  __shared__ unsigned short Ks[2][32 * 192];
  __shared__ unsigned short Vs[2][128 * 32];
  __shared__ unsigned short Ps[4][16 * 32];
  const int tid = threadIdx.x, lane = tid & 63, w = tid >> 6;
  const int wg = (int)blockIdx.x;
  const int lin = (wg & 7) * 128 + (wg >> 3);
  const int h = lin >> 5;
  const int qt = 31 - (lin & 31);
  const int qr0 = qt * 64 + w * 16;
  const int lg = lane >> 4, lm = lane & 15, lm7 = lane & 7;
  const unsigned short* Qh = Qf + h * QKD;
  const int hoff = h * 256;
  const unsigned short* Vh = Vt + (size_t)h * 128 * S_LEN;

  bf16x8 qf[6];
#pragma unroll
  for (int f = 0; f < 6; ++f)
    qf[f] = *reinterpret_cast<const bf16x8*>(
        Qh + (size_t)(qr0 + lm) * QFW + f * 32 + lg * 8);

  f32x4 o[8] = {};
  float l[4] = {};

  auto STAGE = [&](int b, int kp) {
#pragma unroll
    for (int i = 0; i < 3; ++i) {
      int fb = (w * 3 + i) * 64 + lane;
      int row = fb / 24;
      int blk = fb - row * 24;
      int gb = (blk & ~7) | ((blk ^ row) & 7);
      const unsigned short* src = (blk < 16)
          ? KV + (size_t)(kp + row) * KVW + hoff + gb * 8
          : Kr + (size_t)(kp + row) * 64 + (gb - 16) * 8;
      stage16(src, &Ks[b][(w * 3 + i) * 512], lane);
    }
#pragma unroll
    for (int i = 0; i < 2; ++i) {
      int fb = (w * 2 + i) * 64 + lane;
      int row = fb >> 2;
      int blk = fb & 3;
      stage16(Vh + (size_t)row * S_LEN + kp + blk * 8, &Vs[b][(w * 2 + i) * 512], lane);
    }
  };

  const int ntiles = (qt + 1) * 2;
  STAGE(0, 0);
  __syncthreads();
  int buf = 0;
  for (int ti = 0; ti < ntiles; ++ti) {
    const int kp = ti * 32;
    if (ti + 1 < ntiles) STAGE(buf ^ 1, kp + 32);
    if (kp <= qr0 + 15) {
      f32x4 sc[2] = {};
      __builtin_amdgcn_s_setprio(1);
#pragma unroll
      for (int f = 0; f < 6; ++f)
#pragma unroll
        for (int c = 0; c < 2; ++c) {
          int blk = f * 4 + lg;
          int sb = (blk & ~7) | ((blk ^ lm7) & 7);
          bf16x8 kf = *reinterpret_cast<const bf16x8*>(&Ks[buf][(c * 16 + lm) * 192 + sb * 8]);
          sc[c] = __builtin_amdgcn_mfma_f32_16x16x32_bf16(qf[f], kf, sc[c], 0, 0, 0);
        }
      __builtin_amdgcn_s_setprio(0);
      const int rb = qr0 + lg * 4;
#pragma unroll
      for (int r = 0; r < 4; ++r) {
        const int row = rb + r;
        float v0 = fmaf(sc[0][r], SC2F, -32.f); if (kp + lm > row) v0 = -1e9f;
        float v1 = fmaf(sc[1][r], SC2F, -32.f); if (kp + 16 + lm > row) v1 = -1e9f;
        float p0 = ex2(v0), p1 = ex2(v1);
        l[r] += p0 + p1;
        int pr = lg * 4 + r;
        int s3 = pr & 3;
        int b0 = lm >> 3;
        unsigned short* pp = &Ps[w][pr * 32];
        pp[((b0 ^ s3) << 3) + lm7] = f2bf(p0);
        pp[(((2 + b0) ^ s3) << 3) + lm7] = f2bf(p1);
      }
      bf16x8 pa = *reinterpret_cast<const bf16x8*>(
          &Ps[w][lm * 32 + ((lg ^ (lm & 3)) << 3)]);
      __builtin_amdgcn_s_setprio(1);
#pragma unroll
      for (int d = 0; d < 8; ++d) {
        bf16x8 vf = *reinterpret_cast<const bf16x8*>(&Vs[buf][(d * 16 + lm) * 32 + lg * 8]);
        o[d] = __builtin_amdgcn_mfma_f32_16x16x32_bf16(pa, vf, o[d], 0, 0, 0);
      }
      __builtin_amdgcn_s_setprio(0);
    }
    __syncthreads();
    buf ^= 1;
  }
#pragma unroll
  for (int r = 0; r < 4; ++r) {
    float t = l[r];
#pragma unroll
    for (int off = 1; off < 16; off <<= 1) t += __shfl_xor(t, off, 16);
    float inv = 1.0f / t;
    int row = qr0 + lg * 4 + r;
#pragma unroll
    for (int d = 0; d < 8; ++d)
      O[(size_t)row * 4096 + h * 128 + d * 16 + lm] = f2bf(o[d][r] * inv);
  }
}

extern "C" void kernel_launch(void* const* d_in, const int* in_sizes, int n_in,
                              void* d_out, int out_size, void* d_ws, size_t ws_size,
                              hipStream_t stream) {
  const float* hs = (const float*)d_in[0];
  const float* freqs = (const float*)d_in[1];
  const float* q_a_w = (const float*)d_in[2];
  const float* q_a_ln = (const float*)d_in[3];
  const float* q_b_w = (const float*)d_in[4];
  const float* kv_a_w = (const float*)d_in[5];
  const float* kv_a_ln = (const float*)d_in[6];
  const float* kv_b_w = (const float*)d_in[7];
  const float* o_w = (const float*)d_in[8];
  float* out = (float*)d_out;

  char* ws = (char*)d_ws;
  unsigned short* wslot = (unsigned short*)(ws + 0);           // 32 MiB
  unsigned short* hs_bf = (unsigned short*)(ws + 33554432);    // dead after qkv_a
  unsigned short* attnb = (unsigned short*)(ws + 33554432);    // reuse
  float* qkv_part = (float*)(ws + 50331648);                   // 34.6 MiB, dead after rms
  unsigned short* kv_bf = (unsigned short*)(ws + 50331648);    // reuse (alive->attn)
  unsigned short* o_w_bf = (unsigned short*)(ws + 84934656);   // 32 MiB (written in gemm_dual)
  unsigned short* qa_bf = (unsigned short*)(ws + 138412032);
  unsigned short* ckv_bf = (unsigned short*)(ws + 144703488);
  unsigned short* qfullb = (unsigned short*)(ws + 147324928);  // alive->attn
  unsigned short* Vt = (unsigned short*)(ws + 172490752);      // alive->attn
  unsigned short* Kr = (unsigned short*)(ws + 189267968);      // 256 KiB

  dim3 blk(256);
  auto cvt = [&](const float* src, unsigned short* dst, size_t n) {
    int n8 = (int)(n / 8);
    cvt_kernel<<<(n8 + 255) / 256, blk, 0, stream>>>(src, dst, n8);
  };
  auto cvt2 = [&](const float* s1, size_t n1, const float* s2, size_t n2,
                  unsigned short* dst) {
    int n8_1 = (int)(n1 / 8), n8_t = (int)((n1 + n2) / 8);
    cvt2_kernel<<<(n8_t + 255) / 256, blk, 0, stream>>>(s1, n8_1, s2, dst, n8_t);
  };

  cvt(hs, hs_bf, (size_t)S_LEN * HDIM);
  cvt2(q_a_w, (size_t)RQ_ * HDIM, kv_a_w, (size_t)CKV_W * HDIM, wslot);
  gemm_bf<false, true><<<dim3(17, S_LEN / 128, 2), blk, 0, stream>>>(
      hs_bf, HDIM, wslot, HDIM, qkv_part, NQKV, NQKV, HDIM / 2);
  rms_fused<<<S_LEN, blk, 0, stream>>>(qkv_part, q_a_ln, kv_a_ln, freqs,
                                       qa_bf, ckv_bf, Kr);
  cvt2(q_b_w, (size_t)QFW * RQ_, kv_b_w, (size_t)KVW * 512, wslot);
  // q_b (768) + kv_b (1024) + o_w cvt tail (256) in one dispatch
  gemm_dual<<<dim3(2048), blk, 0, stream>>>(
      qa_bf, RQ_, wslot, RQ_, qfullb, QFW, RQ_, 768,
      ckv_bf, 512, wslot + (size_t)QFW * RQ_, 512, kv_bf, KVW, 512, 1024, Vt,
      o_w, o_w_bf, (int)((size_t)HDIM * HDIM / 8));
  rope_q_kernel<<<(NHEAD * S_LEN * 32 + 255) / 256, blk, 0, stream>>>(qfullb, freqs);
  attn_kernel<<<dim3(1024), blk, 0, stream>>>(qfullb, kv_bf, Kr, Vt, attnb);
  gemm_bf<false, false><<<dim3(HDIM / 128, S_LEN / 128), blk, 0, stream>>>(
      attnb, HDIM, o_w_bf, HDIM, out, HDIM, HDIM, HDIM);
}